// Round 6
// baseline (205.712 us; speedup 1.0000x reference)
//
#include <hip/hip_runtime.h>

// EncoderLayer: pre-norm MHA + FFN, B=2 S=2048 D=768 H=12 DFF=2048, fp32 I/O,
// bf16 MFMA internals. Pipeline:
//   pre (weights->bf16 + bias concat + LN1), QKV-GEMM(fused N=2304, Q pre-scaled),
//   flash-attn (split-KV in block), Wo-GEMM+res, LN2, FFN1+relu, FFN2+res -> d_out
#define SS   2048
#define DD   768
#define HH   12
#define DFFF 2048
#define BSR  4096      // B*S
#define QKV_LD 2304

typedef __attribute__((ext_vector_type(8))) short bf16x8;
typedef __attribute__((ext_vector_type(4))) float f32x4;

__device__ __forceinline__ unsigned short f2b(float f) {
  union { float f; unsigned u; } x; x.f = f;
  unsigned r = (x.u + 0x7FFFu + ((x.u >> 16) & 1u)) >> 16;
  return (unsigned short)r;
}

__device__ __forceinline__ unsigned cvtpk(float lo, float hi) {
  unsigned r;
  asm("v_cvt_pk_bf16_f32 %0, %1, %2" : "=v"(r) : "v"(lo), "v"(hi));
  return r;
}

__device__ __forceinline__ void gload_lds16(const void* g, void* l) {
  __builtin_amdgcn_global_load_lds(
      (const __attribute__((address_space(1))) unsigned int*)g,
      (__attribute__((address_space(3))) unsigned int*)l,
      16, 0, 0);
}

// ---------------- LayerNorm row (torch semantics: ddof=1, eps on std) -------
__device__ __forceinline__ void ln_row(const float* __restrict__ xr,
                                       const float* __restrict__ alpha,
                                       const float* __restrict__ beta,
                                       unsigned short* __restrict__ orow, int lane) {
  float4 v[3];
#pragma unroll
  for (int g = 0; g < 3; ++g) v[g] = *(const float4*)&xr[lane * 12 + g * 4];
  float sum = 0.f;
#pragma unroll
  for (int g = 0; g < 3; ++g) sum += v[g].x + v[g].y + v[g].z + v[g].w;
#pragma unroll
  for (int off = 1; off < 64; off <<= 1) sum += __shfl_xor(sum, off);
  float mu = sum * (1.0f / 768.0f);
  float ss = 0.f;
#pragma unroll
  for (int g = 0; g < 3; ++g) {
    float a0 = v[g].x - mu, a1 = v[g].y - mu, a2 = v[g].z - mu, a3 = v[g].w - mu;
    ss += a0 * a0 + a1 * a1 + a2 * a2 + a3 * a3;
  }
#pragma unroll
  for (int off = 1; off < 64; off <<= 1) ss += __shfl_xor(ss, off);
  float sd = sqrtf(ss * (1.0f / 767.0f));
  float inv = 1.0f / (sd + 1e-6f);
#pragma unroll
  for (int g = 0; g < 3; ++g) {
    float4 al = *(const float4*)&alpha[lane * 12 + g * 4];
    float4 be = *(const float4*)&beta[lane * 12 + g * 4];
    uint2 pk;
    pk.x = cvtpk(al.x * (v[g].x - mu) * inv + be.x, al.y * (v[g].y - mu) * inv + be.y);
    pk.y = cvtpk(al.z * (v[g].z - mu) * inv + be.z, al.w * (v[g].w - mu) * inv + be.w);
    *(uint2*)&orow[lane * 12 + g * 4] = pk;
  }
}

// ------- merged: weight fp32->bf16 + bias concat + LN1 (one launch) ---------
__global__ __launch_bounds__(256) void pre_k(const float* __restrict__ Wq,
                                             const float* __restrict__ Wk,
                                             const float* __restrict__ Wv,
                                             const float* __restrict__ Wo,
                                             const float* __restrict__ W1,
                                             const float* __restrict__ W2,
                                             const float* __restrict__ bq,
                                             const float* __restrict__ bk,
                                             const float* __restrict__ bv,
                                             const float* __restrict__ x,
                                             const float* __restrict__ alpha,
                                             const float* __restrict__ beta,
                                             unsigned short* __restrict__ wqkv,
                                             unsigned short* __restrict__ wo_b,
                                             unsigned short* __restrict__ w1_b,
                                             unsigned short* __restrict__ w2_b,
                                             float* __restrict__ bqkv,
                                             unsigned short* __restrict__ n_b) {
  const int blk = blockIdx.x;
  const float* src;
  unsigned short* dst;
  long off;
  if (blk < 1728) {            // Wq/Wk/Wv -> wqkv rows [0,2304)
    int r = blk / 576;
    src = r == 0 ? Wq : r == 1 ? Wk : Wv;
    dst = wqkv + (long)r * 589824;
    off = (long)(blk - r * 576) * 1024 + threadIdx.x * 4;
  } else if (blk < 2304) {
    src = Wo; dst = wo_b; off = (long)(blk - 1728) * 1024 + threadIdx.x * 4;
  } else if (blk < 3840) {
    src = W1; dst = w1_b; off = (long)(blk - 2304) * 1024 + threadIdx.x * 4;
  } else if (blk < 5376) {
    src = W2; dst = w2_b; off = (long)(blk - 3840) * 1024 + threadIdx.x * 4;
  } else if (blk == 5376) {    // bias concat
    for (int k = threadIdx.x; k < 2304; k += 256)
      bqkv[k] = k < 768 ? bq[k] : k < 1536 ? bk[k - 768] : bv[k - 1536];
    return;
  } else {                     // LN1: 4 rows per block
    int row = (blk - 5377) * 4 + (threadIdx.x >> 6);
    ln_row(x + (long)row * DD, alpha, beta, n_b + (long)row * DD, threadIdx.x & 63);
    return;
  }
  float4 v = *(const float4*)&src[off];
  uint2 pk;
  pk.x = cvtpk(v.x, v.y);
  pk.y = cvtpk(v.z, v.w);
  *(uint2*)&dst[off] = pk;
}

// ---------------- LN2 standalone ----------------
__global__ __launch_bounds__(256) void layernorm_k(const float* __restrict__ x,
                                                   const float* __restrict__ alpha,
                                                   const float* __restrict__ beta,
                                                   unsigned short* __restrict__ outb) {
  int row = blockIdx.x * 4 + (threadIdx.x >> 6);
  ln_row(x + (long)row * DD, alpha, beta, outb + (long)row * DD, threadIdx.x & 63);
}

// ---------------- bf16 GEMM: C[M,N] = A[M,K] * W[N,K]^T (+bias,+res,relu) ----
// 128xBN tile, BK=64, 4 waves, global_load_lds staging (m97 structure).
// QSC: scale cols<768 by 0.125*log2(e) (Q pre-scale for exp2-domain attn).
template <int BN, bool RELU, bool RES, bool OUTB, bool QSC>
__global__ __launch_bounds__(256, BN == 64 ? 4 : 2)
void gemm_bt(const unsigned short* __restrict__ A,
             const unsigned short* __restrict__ W,
             const float* __restrict__ bias,
             const float* __restrict__ res,
             void* __restrict__ outp,
             int M, int N, int K) {
  __shared__ __align__(16) unsigned short As[128 * 64];
  __shared__ __align__(16) unsigned short Bs[BN * 64];
  constexpr int NF = BN / 32;   // 16-wide col frags per wave
  const int t = threadIdx.x;
  const int lane = t & 63;
  const int w = t >> 6;
  const int wr = w >> 1, wc = w & 1;
  const int l15 = lane & 15, l4 = lane >> 4;
  const long brow = (long)blockIdx.y * 128;
  const long bcol = (long)blockIdx.x * BN;
  f32x4 acc[4][NF] = {};
  const int r0 = t >> 3;        // 0..31
  const int c8 = (t & 7) * 8;   // 0..56

  for (int k0 = 0; k0 < K; k0 += 64) {
    __syncthreads();
#pragma unroll
    for (int p = 0; p < 4; ++p)
      gload_lds16(&A[(brow + p * 32 + r0) * (long)K + k0 + c8],
                  (char*)As + p * 4096 + w * 1024);
#pragma unroll
    for (int p = 0; p < BN / 32; ++p)
      gload_lds16(&W[(bcol + p * 32 + r0) * (long)K + k0 + c8],
                  (char*)Bs + p * 4096 + w * 1024);
    __syncthreads();
#pragma unroll
    for (int ks = 0; ks < 2; ++ks) {
      bf16x8 a[4], b[NF];
#pragma unroll
      for (int m = 0; m < 4; ++m)
        a[m] = *(const bf16x8*)&As[(wr * 64 + m * 16 + l15) * 64 + ks * 32 + l4 * 8];
#pragma unroll
      for (int n = 0; n < NF; ++n)
        b[n] = *(const bf16x8*)&Bs[(wc * (BN / 2) + n * 16 + l15) * 64 + ks * 32 + l4 * 8];
#pragma unroll
      for (int m = 0; m < 4; ++m)
#pragma unroll
        for (int n = 0; n < NF; ++n)
          acc[m][n] = __builtin_amdgcn_mfma_f32_16x16x32_bf16(a[m], b[n], acc[m][n], 0, 0, 0);
    }
  }
#pragma unroll
  for (int n = 0; n < NF; ++n) {
    const long col = bcol + wc * (BN / 2) + n * 16 + l15;
    const float bv = bias[col];
    const float sc = (QSC && col < 768) ? 0.18033688f : 1.0f;
#pragma unroll
    for (int m = 0; m < 4; ++m) {
      const long row0 = brow + wr * 64 + m * 16 + l4 * 4;
#pragma unroll
      for (int r = 0; r < 4; ++r) {
        float v = acc[m][n][r] + bv;
        if (RELU) v = fmaxf(v, 0.0f);
        if (QSC) v *= sc;
        long o = (row0 + r) * (long)N + col;
        if (RES) v += res[o];
        if (OUTB) ((unsigned short*)outp)[o] = f2b(v);
        else ((float*)outp)[o] = v;
      }
    }
  }
}

// ---------------- flash attention v6: split-KV within block -----------------
// 512 threads = 2 groups x 4 waves. Group g handles keys [g*1024, g*1024+1024).
// Per group: swapped QK^T (Q pre-scaled), K via global_load_lds (dbuf, XOR-swz),
// V transposed into key-permuted LDS (lane-local P), exp2 softmax, defer-max.
// Final flash-merge of the two partials through LDS (group 0 writes ctx).
// key->pos permutation: pos = (k5, k3, k2, k4, k1, k0)
__global__ __launch_bounds__(512, 4) void attn_kernel(const unsigned short* __restrict__ qkv,
                                                      const int* __restrict__ mask,
                                                      unsigned short* __restrict__ ctx) {
  __shared__ __align__(16) unsigned short Ks[2][2][64 * 64];  // [grp][dbuf]
  __shared__ __align__(16) unsigned short Vt[2][2][64 * 64];  // [grp][dbuf]
  __shared__ int tfl[32];
  __shared__ unsigned bmsh;
  const int t = threadIdx.x, lane = t & 63;
  const int grp = t >> 8;            // 0,1
  const int wg = (t >> 6) & 3;       // wave within group
  const int tg = t & 255;            // thread within group
  const int l15 = lane & 15, l4 = lane >> 4;
  const int kvoff = grp * 1024;      // key offset of this group
  // XCD-chunked swizzle: 32 q-tiles of one (b,h) land on one XCD's L2
  const int u = (blockIdx.x & 7) * 96 + (blockIdx.x >> 3);
  const int qt = u & 31;
  const int h = (u >> 5) % 12;
  const int b = u / 384;
  const long rowB = (long)b * SS;

  // ---- per-block mask bitmap: bit kb = "tile kb fully unmasked" ----
  if (t < 256) {
    const int* mb = &mask[b * SS + t * 8];
    int4 a0 = *(const int4*)mb;
    int4 a1 = *(const int4*)(mb + 4);
    int allv = (a0.x && a0.y && a0.z && a0.w && a1.x && a1.y && a1.z && a1.w) ? 1 : 0;
    allv &= __shfl_xor(allv, 1);
    allv &= __shfl_xor(allv, 2);
    allv &= __shfl_xor(allv, 4);
    if ((t & 7) == 0) tfl[t >> 3] = allv;
  }
  __syncthreads();
  if (t < 64) {
    int v = (t < 32) ? tfl[t] : 1;
    unsigned long long bl = __ballot(v);
    if (t == 0) bmsh = (unsigned)bl;
  }

  // Q fragment (B operand): lane l15 = q, elems d = ks*32 + l4*8 + j
  bf16x8 aq[2];
#pragma unroll
  for (int ks = 0; ks < 2; ++ks)
    aq[ks] = *(const bf16x8*)&qkv[(rowB + qt * 64 + wg * 16 + l15) * QKV_LD +
                                  h * 64 + ks * 32 + l4 * 8];

  // K staging (gload_lds linear dest; XOR swizzle folded into global src col)
  const int krow = wg * 8 + (lane >> 3);                         // +p*32
  const int kdo = (((lane & 7) ^ (lane >> 3)) & 7) << 3;         // shorts
  const unsigned short* kgbase = &qkv[(rowB + kvoff + krow) * QKV_LD + 768 + h * 64 + kdo];
  const int kread_swz = (l15 & 7) << 4;

  // V handling (per group: 256 threads stage 64 keys x 64 d)
  const unsigned short* vgbase = &qkv[(rowB + kvoff + (tg >> 3)) * QKV_LD + 1536 +
                                      h * 64 + (tg & 7) * 8];
  const int vd0 = (tg & 7) * 8;
  const int vpar = (tg >> 3) & 1;
  const int K0 = (tg >> 3) & 30;

  uint4 va, vb;
  f32x4 o[4] = {};
  float mrun = -1e30f, lsum = 0.f;

#define VWRITE(buf)                                                             \
  { _Pragma("unroll") for (int p = 0; p < 2; ++p) {                             \
      uint4 vv = p ? vb : va;                                                   \
      unsigned own[4] = {vv.x, vv.y, vv.z, vv.w};                               \
      const int K0p = p * 32 + K0;                                              \
      const int pp = ((K0p & 32) | ((K0p & 12) << 1) | ((K0p & 16) >> 2) | (K0p & 2)) >> 1; \
      _Pragma("unroll") for (int j = 0; j < 4; ++j) {                           \
        unsigned part = __shfl_xor(own[j], 8);                                  \
        unsigned val = vpar ? ((part >> 16) | (own[j] & 0xffff0000u))           \
                            : ((own[j] & 0xffffu) | (part << 16));              \
        int d = vd0 + 2 * j + vpar;                                             \
        int swz = (((2 * j + vpar) ^ (tg & 7)) & 7) << 4;                       \
        *(unsigned*)((char*)(buf) + d * 128 + ((pp * 4) ^ swz)) = val;          \
      } } }

  // ---- prologue: stage tile 0 of this group ----
#pragma unroll
  for (int p = 0; p < 2; ++p)
    gload_lds16(kgbase + (long)p * 32 * QKV_LD, (char*)Ks[grp][0] + p * 4096 + wg * 1024);
  va = *(const uint4*)(vgbase);
  vb = *(const uint4*)(vgbase + (long)32 * QKV_LD);
  VWRITE(Vt[grp][0]);
  __syncthreads();
  const unsigned bm = bmsh;

  for (int i = 0; i < 16; ++i) {
    const int bi = i & 1;
    const char* Kc = (const char*)Ks[grp][bi];
    const char* Vc = (const char*)Vt[grp][bi];
    // prefetch next tile (K direct-to-LDS, V to regs)
    if (i < 15) {
#pragma unroll
      for (int p = 0; p < 2; ++p)
        gload_lds16(kgbase + ((long)(i + 1) * 64 + p * 32) * QKV_LD,
                    (char*)Ks[grp][bi ^ 1] + p * 4096 + wg * 1024);
      va = *(const uint4*)(vgbase + (long)(i + 1) * 64 * QKV_LD);
      vb = *(const uint4*)(vgbase + ((long)(i + 1) * 64 + 32) * QKV_LD);
    }
    // ---- QK^T (swapped): S^T, col=l15=q, key=cg*16+l4*4+r; pre-scaled ----
    f32x4 s[4] = {};
    __builtin_amdgcn_s_setprio(1);
#pragma unroll
    for (int ks = 0; ks < 2; ++ks)
#pragma unroll
      for (int cg = 0; cg < 4; ++cg) {
        bf16x8 ak = *(const bf16x8*)(Kc + (cg * 16 + l15) * 128 +
                                     ((ks * 64 + l4 * 16) ^ kread_swz));
        s[cg] = __builtin_amdgcn_mfma_f32_16x16x32_bf16(ak, aq[ks], s[cg], 0, 0, 0);
      }
    __builtin_amdgcn_s_setprio(0);
    // ---- rare masked-tile path (uniform branch; never taken for all-ones) --
    if (__builtin_expect(!((bm >> (grp * 16 + i)) & 1), 0)) {
      const int* mb2 = &mask[b * SS + kvoff + i * 64 + l4 * 4];
#pragma unroll
      for (int cg = 0; cg < 4; ++cg) {
        int4 mm = *(const int4*)(mb2 + cg * 16);
        int mi[4] = {mm.x, mm.y, mm.z, mm.w};
#pragma unroll
        for (int r = 0; r < 4; ++r) s[cg][r] += mi[r] ? 0.f : -1.44269504e9f;
      }
    }
    // ---- online softmax in exp2 domain (per-q stats, q=l15) ----
    float pmax = -3e38f;
#pragma unroll
    for (int cg = 0; cg < 4; ++cg)
#pragma unroll
      for (int r = 0; r < 4; ++r) pmax = fmaxf(pmax, s[cg][r]);
    pmax = fmaxf(pmax, __shfl_xor(pmax, 16));
    pmax = fmaxf(pmax, __shfl_xor(pmax, 32));
    if (!__all(pmax <= mrun + 8.0f)) {   // defer-max (THR=8, exp2 domain)
      float mnew = fmaxf(mrun, pmax);
      float fac = __builtin_amdgcn_exp2f(mrun - mnew);
      lsum *= fac;
#pragma unroll
      for (int mg = 0; mg < 4; ++mg)
#pragma unroll
        for (int r = 0; r < 4; ++r) o[mg][r] *= fac;
      mrun = mnew;
    }
    float sum = 0.f;
#pragma unroll
    for (int cg = 0; cg < 4; ++cg)
#pragma unroll
      for (int r = 0; r < 4; ++r) {
        float p2 = __builtin_amdgcn_exp2f(s[cg][r] - mrun);
        s[cg][r] = p2;
        sum += p2;
      }
    sum += __shfl_xor(sum, 16);
    sum += __shfl_xor(sum, 32);
    lsum += sum;
    // ---- PV: O^T[d][q] += V^T . P^T ; P fragment is lane-local ----
    __builtin_amdgcn_s_setprio(1);
#pragma unroll
    for (int ks = 0; ks < 2; ++ks) {
      union { unsigned uu[4]; bf16x8 b8; } bp;
      bp.uu[0] = cvtpk(s[2 * ks][0], s[2 * ks][1]);
      bp.uu[1] = cvtpk(s[2 * ks][2], s[2 * ks][3]);
      bp.uu[2] = cvtpk(s[2 * ks + 1][0], s[2 * ks + 1][1]);
      bp.uu[3] = cvtpk(s[2 * ks + 1][2], s[2 * ks + 1][3]);
#pragma unroll
      for (int mg = 0; mg < 4; ++mg) {
        const int dv = mg * 16 + l15;
        const int sv = ((dv ^ (dv >> 3)) & 7) << 4;
        bf16x8 av = *(const bf16x8*)(Vc + dv * 128 + ((ks * 64 + l4 * 16) ^ sv));
        o[mg] = __builtin_amdgcn_mfma_f32_16x16x32_bf16(av, bp.b8, o[mg], 0, 0, 0);
      }
    }
    __builtin_amdgcn_s_setprio(0);
    // ---- write next V tile (vreg landed under compute) ----
    if (i < 15) VWRITE(Vt[grp][bi ^ 1]);
    __syncthreads();
  }

  // ---- flash-merge of the two KV-half partials (via LDS, reuse Ks) ----
  // o1s: [q][d] fp32 padded to 65, then m1s[64], l1s[64]
  float* o1s = (float*)(&Ks[0][0][0]);
  float* m1s = o1s + 64 * 65;
  float* l1s = m1s + 64;
  const int q = wg * 16 + l15;
  if (grp == 1) {
#pragma unroll
    for (int mg = 0; mg < 4; ++mg) {
      float4 tv = {o[mg][0], o[mg][1], o[mg][2], o[mg][3]};
      *(float4*)&o1s[q * 65 + mg * 16 + l4 * 4] = tv;
    }
    if (l4 == 0) { m1s[q] = mrun; l1s[q] = lsum; }
  }
  __syncthreads();
  if (grp == 0) {
    const float m1 = m1s[q], l1 = l1s[q];
    const float m = fmaxf(mrun, m1);
    const float f0 = __builtin_amdgcn_exp2f(mrun - m);
    const float f1 = __builtin_amdgcn_exp2f(m1 - m);
    const float inv = 1.0f / (lsum * f0 + l1 * f1);
    const long obase = (rowB + qt * 64 + wg * 16 + l15) * DD + h * 64 + l4 * 4;
#pragma unroll
    for (int mg = 0; mg < 4; ++mg) {
      float4 o1v = *(const float4*)&o1s[q * 65 + mg * 16 + l4 * 4];
      float r0v = (o[mg][0] * f0 + o1v.x * f1) * inv;
      float r1v = (o[mg][1] * f0 + o1v.y * f1) * inv;
      float r2v = (o[mg][2] * f0 + o1v.z * f1) * inv;
      float r3v = (o[mg][3] * f0 + o1v.w * f1) * inv;
      *(unsigned*)&ctx[obase + mg * 16] = cvtpk(r0v, r1v);
      *(unsigned*)&ctx[obase + mg * 16 + 2] = cvtpk(r2v, r3v);
    }
  }
#undef VWRITE
}

// ---------------- workspace layout (bytes) ----------------
static const size_t OFF_WQKV = 0;          // 2304*768*2  = 3538944
static const size_t OFF_WO = 3538944;      // 768*768*2   = 1179648
static const size_t OFF_W1 = 4718592;      // 2048*768*2  = 3145728
static const size_t OFF_W2 = 7864320;      // 768*2048*2  = 3145728
static const size_t OFF_BQKV = 11010048;   // 2304*4
static const size_t OFF_N = 11019264;      // 4096*768*2  (reused for n2)
static const size_t OFF_QKV = 17310720;    // 4096*2304*2 (reused for h)
static const size_t OFF_CTX = 36185088;    // 4096*768*2
static const size_t OFF_X1 = 42476544;     // 4096*768*4
// total = 55059456 bytes

extern "C" void kernel_launch(void* const* d_in, const int* in_sizes, int n_in,
                              void* d_out, int out_size, void* d_ws, size_t ws_size,
                              hipStream_t stream) {
  (void)in_sizes; (void)n_in; (void)out_size; (void)ws_size;
  const float* x = (const float*)d_in[0];
  const int* mask = (const int*)d_in[1];
  const float* Wq = (const float*)d_in[2];
  const float* bq = (const float*)d_in[3];
  const float* Wk = (const float*)d_in[4];
  const float* bk = (const float*)d_in[5];
  const float* Wv = (const float*)d_in[6];
  const float* bv = (const float*)d_in[7];
  const float* Wo = (const float*)d_in[8];
  const float* bo = (const float*)d_in[9];
  const float* W1 = (const float*)d_in[10];
  const float* b1 = (const float*)d_in[11];
  const float* W2 = (const float*)d_in[12];
  const float* b2 = (const float*)d_in[13];
  const float* alpha = (const float*)d_in[14];
  const float* beta = (const float*)d_in[15];

  char* ws = (char*)d_ws;
  unsigned short* wqkv = (unsigned short*)(ws + OFF_WQKV);
  unsigned short* wo_b = (unsigned short*)(ws + OFF_WO);
  unsigned short* w1_b = (unsigned short*)(ws + OFF_W1);
  unsigned short* w2_b = (unsigned short*)(ws + OFF_W2);
  float* bqkv = (float*)(ws + OFF_BQKV);
  unsigned short* n_b = (unsigned short*)(ws + OFF_N);
  unsigned short* qkv_b = (unsigned short*)(ws + OFF_QKV);
  unsigned short* h_b = qkv_b;  // reuse after attention
  unsigned short* ctx_b = (unsigned short*)(ws + OFF_CTX);
  float* x1_f = (float*)(ws + OFF_X1);
  float* out_f = (float*)d_out;

  // weights->bf16 + bias concat + LN1 in one launch (5377 cvt/bias + 1024 LN)
  pre_k<<<6401, 256, 0, stream>>>(Wq, Wk, Wv, Wo, W1, W2, bq, bk, bv,
                                  x, alpha, beta, wqkv, wo_b, w1_b, w2_b, bqkv, n_b);
  // fused QKV GEMM: [4096,768] x [2304,768]^T -> [4096,2304] bf16, Q pre-scaled
  gemm_bt<128, false, false, true, true><<<dim3(18, 32), 256, 0, stream>>>(
      n_b, wqkv, bqkv, nullptr, qkv_b, BSR, QKV_LD, DD);
  // attention (split-KV in block: 512 threads)
  attn_kernel<<<768, 512, 0, stream>>>(qkv_b, mask, ctx_b);
  // Wo GEMM + residual(x) -> x1 fp32 (BN=64: 384 blocks)
  gemm_bt<64, false, true, false, false><<<dim3(12, 32), 256, 0, stream>>>(
      ctx_b, wo_b, bo, x, x1_f, BSR, DD, DD);
  // LN2
  layernorm_k<<<1024, 256, 0, stream>>>(x1_f, alpha, beta, n_b);
  // FFN1 + relu -> h bf16
  gemm_bt<128, true, false, true, false><<<dim3(16, 32), 256, 0, stream>>>(
      n_b, w1_b, b1, nullptr, h_b, BSR, DFFF, DD);
  // FFN2 + residual(x1) -> out fp32 (BN=64: 384 blocks)
  gemm_bt<64, false, true, false, false><<<dim3(12, 32), 256, 0, stream>>>(
      h_b, w2_b, b2, x1_f, out_f, BSR, DD, DFFF);
}

// Round 7
// 202.069 us; speedup vs baseline: 1.0180x; 1.0180x over previous
//
#include <hip/hip_runtime.h>

// EncoderLayer: pre-norm MHA + FFN, B=2 S=2048 D=768 H=12 DFF=2048, fp32 I/O,
// bf16 MFMA internals. Pipeline:
//   pre (weights->bf16 + bias concat + LN1), QKV-GEMM(fused N=2304, Q pre-scaled),
//   flash-attn (split-KV across blocks) + merge, Wo-GEMM+res, LN2, FFN1+relu,
//   FFN2+res -> d_out
#define SS   2048
#define DD   768
#define HH   12
#define DFFF 2048
#define BSR  4096      // B*S
#define QKV_LD 2304

typedef __attribute__((ext_vector_type(8))) short bf16x8;
typedef __attribute__((ext_vector_type(4))) float f32x4;

__device__ __forceinline__ unsigned short f2b(float f) {
  union { float f; unsigned u; } x; x.f = f;
  unsigned r = (x.u + 0x7FFFu + ((x.u >> 16) & 1u)) >> 16;
  return (unsigned short)r;
}

__device__ __forceinline__ unsigned cvtpk(float lo, float hi) {
  unsigned r;
  asm("v_cvt_pk_bf16_f32 %0, %1, %2" : "=v"(r) : "v"(lo), "v"(hi));
  return r;
}

__device__ __forceinline__ void gload_lds16(const void* g, void* l) {
  __builtin_amdgcn_global_load_lds(
      (const __attribute__((address_space(1))) unsigned int*)g,
      (__attribute__((address_space(3))) unsigned int*)l,
      16, 0, 0);
}

// ---------------- LayerNorm row (torch semantics: ddof=1, eps on std) -------
__device__ __forceinline__ void ln_row(const float* __restrict__ xr,
                                       const float* __restrict__ alpha,
                                       const float* __restrict__ beta,
                                       unsigned short* __restrict__ orow, int lane) {
  float4 v[3];
#pragma unroll
  for (int g = 0; g < 3; ++g) v[g] = *(const float4*)&xr[lane * 12 + g * 4];
  float sum = 0.f;
#pragma unroll
  for (int g = 0; g < 3; ++g) sum += v[g].x + v[g].y + v[g].z + v[g].w;
#pragma unroll
  for (int off = 1; off < 64; off <<= 1) sum += __shfl_xor(sum, off);
  float mu = sum * (1.0f / 768.0f);
  float ss = 0.f;
#pragma unroll
  for (int g = 0; g < 3; ++g) {
    float a0 = v[g].x - mu, a1 = v[g].y - mu, a2 = v[g].z - mu, a3 = v[g].w - mu;
    ss += a0 * a0 + a1 * a1 + a2 * a2 + a3 * a3;
  }
#pragma unroll
  for (int off = 1; off < 64; off <<= 1) ss += __shfl_xor(ss, off);
  float sd = sqrtf(ss * (1.0f / 767.0f));
  float inv = 1.0f / (sd + 1e-6f);
#pragma unroll
  for (int g = 0; g < 3; ++g) {
    float4 al = *(const float4*)&alpha[lane * 12 + g * 4];
    float4 be = *(const float4*)&beta[lane * 12 + g * 4];
    uint2 pk;
    pk.x = cvtpk(al.x * (v[g].x - mu) * inv + be.x, al.y * (v[g].y - mu) * inv + be.y);
    pk.y = cvtpk(al.z * (v[g].z - mu) * inv + be.z, al.w * (v[g].w - mu) * inv + be.w);
    *(uint2*)&orow[lane * 12 + g * 4] = pk;
  }
}

// ------- merged: weight fp32->bf16 + bias concat + LN1 (one launch) ---------
__global__ __launch_bounds__(256) void pre_k(const float* __restrict__ Wq,
                                             const float* __restrict__ Wk,
                                             const float* __restrict__ Wv,
                                             const float* __restrict__ Wo,
                                             const float* __restrict__ W1,
                                             const float* __restrict__ W2,
                                             const float* __restrict__ bq,
                                             const float* __restrict__ bk,
                                             const float* __restrict__ bv,
                                             const float* __restrict__ x,
                                             const float* __restrict__ alpha,
                                             const float* __restrict__ beta,
                                             unsigned short* __restrict__ wqkv,
                                             unsigned short* __restrict__ wo_b,
                                             unsigned short* __restrict__ w1_b,
                                             unsigned short* __restrict__ w2_b,
                                             float* __restrict__ bqkv,
                                             unsigned short* __restrict__ n_b) {
  const int blk = blockIdx.x;
  const float* src;
  unsigned short* dst;
  long off;
  if (blk < 1728) {            // Wq/Wk/Wv -> wqkv rows [0,2304)
    int r = blk / 576;
    src = r == 0 ? Wq : r == 1 ? Wk : Wv;
    dst = wqkv + (long)r * 589824;
    off = (long)(blk - r * 576) * 1024 + threadIdx.x * 4;
  } else if (blk < 2304) {
    src = Wo; dst = wo_b; off = (long)(blk - 1728) * 1024 + threadIdx.x * 4;
  } else if (blk < 3840) {
    src = W1; dst = w1_b; off = (long)(blk - 2304) * 1024 + threadIdx.x * 4;
  } else if (blk < 5376) {
    src = W2; dst = w2_b; off = (long)(blk - 3840) * 1024 + threadIdx.x * 4;
  } else if (blk == 5376) {    // bias concat
    for (int k = threadIdx.x; k < 2304; k += 256)
      bqkv[k] = k < 768 ? bq[k] : k < 1536 ? bk[k - 768] : bv[k - 1536];
    return;
  } else {                     // LN1: 4 rows per block
    int row = (blk - 5377) * 4 + (threadIdx.x >> 6);
    ln_row(x + (long)row * DD, alpha, beta, n_b + (long)row * DD, threadIdx.x & 63);
    return;
  }
  float4 v = *(const float4*)&src[off];
  uint2 pk;
  pk.x = cvtpk(v.x, v.y);
  pk.y = cvtpk(v.z, v.w);
  *(uint2*)&dst[off] = pk;
}

// ---------------- LN2 standalone ----------------
__global__ __launch_bounds__(256) void layernorm_k(const float* __restrict__ x,
                                                   const float* __restrict__ alpha,
                                                   const float* __restrict__ beta,
                                                   unsigned short* __restrict__ outb) {
  int row = blockIdx.x * 4 + (threadIdx.x >> 6);
  ln_row(x + (long)row * DD, alpha, beta, outb + (long)row * DD, threadIdx.x & 63);
}

// ---------------- bf16 GEMM: C[M,N] = A[M,K] * W[N,K]^T (+bias,+res,relu) ----
// 128xBN tile, BK=64, 4 waves, global_load_lds staging (m97 structure).
// QSC: scale cols<768 by 0.125*log2(e) (Q pre-scale for exp2-domain attn).
template <int BN, bool RELU, bool RES, bool OUTB, bool QSC>
__global__ __launch_bounds__(256, BN == 64 ? 4 : 2)
void gemm_bt(const unsigned short* __restrict__ A,
             const unsigned short* __restrict__ W,
             const float* __restrict__ bias,
             const float* __restrict__ res,
             void* __restrict__ outp,
             int M, int N, int K) {
  __shared__ __align__(16) unsigned short As[128 * 64];
  __shared__ __align__(16) unsigned short Bs[BN * 64];
  constexpr int NF = BN / 32;   // 16-wide col frags per wave
  const int t = threadIdx.x;
  const int lane = t & 63;
  const int w = t >> 6;
  const int wr = w >> 1, wc = w & 1;
  const int l15 = lane & 15, l4 = lane >> 4;
  const long brow = (long)blockIdx.y * 128;
  const long bcol = (long)blockIdx.x * BN;
  f32x4 acc[4][NF] = {};
  const int r0 = t >> 3;        // 0..31
  const int c8 = (t & 7) * 8;   // 0..56

  for (int k0 = 0; k0 < K; k0 += 64) {
    __syncthreads();
#pragma unroll
    for (int p = 0; p < 4; ++p)
      gload_lds16(&A[(brow + p * 32 + r0) * (long)K + k0 + c8],
                  (char*)As + p * 4096 + w * 1024);
#pragma unroll
    for (int p = 0; p < BN / 32; ++p)
      gload_lds16(&W[(bcol + p * 32 + r0) * (long)K + k0 + c8],
                  (char*)Bs + p * 4096 + w * 1024);
    __syncthreads();
#pragma unroll
    for (int ks = 0; ks < 2; ++ks) {
      bf16x8 a[4], b[NF];
#pragma unroll
      for (int m = 0; m < 4; ++m)
        a[m] = *(const bf16x8*)&As[(wr * 64 + m * 16 + l15) * 64 + ks * 32 + l4 * 8];
#pragma unroll
      for (int n = 0; n < NF; ++n)
        b[n] = *(const bf16x8*)&Bs[(wc * (BN / 2) + n * 16 + l15) * 64 + ks * 32 + l4 * 8];
#pragma unroll
      for (int m = 0; m < 4; ++m)
#pragma unroll
        for (int n = 0; n < NF; ++n)
          acc[m][n] = __builtin_amdgcn_mfma_f32_16x16x32_bf16(a[m], b[n], acc[m][n], 0, 0, 0);
    }
  }
#pragma unroll
  for (int n = 0; n < NF; ++n) {
    const long col = bcol + wc * (BN / 2) + n * 16 + l15;
    const float bv = bias[col];
    const float sc = (QSC && col < 768) ? 0.18033688f : 1.0f;
#pragma unroll
    for (int m = 0; m < 4; ++m) {
      const long row0 = brow + wr * 64 + m * 16 + l4 * 4;
#pragma unroll
      for (int r = 0; r < 4; ++r) {
        float v = acc[m][n][r] + bv;
        if (RELU) v = fmaxf(v, 0.0f);
        if (QSC) v *= sc;
        long o = (row0 + r) * (long)N + col;
        if (RES) v += res[o];
        if (OUTB) ((unsigned short*)outp)[o] = f2b(v);
        else ((float*)outp)[o] = v;
      }
    }
  }
}

// ---------------- flash attention v7: split-KV across blocks ----------------
// Grid 1536 = (b,h,qt,half); 256 threads, 4 waves. Each block does 16 key
// tiles of its half. Swapped QK^T (Q pre-scaled), K via global_load_lds
// (dbuf, XOR-swz), V transposed into key-permuted LDS (lane-local P), exp2
// softmax, defer-max. Epilogue: normalized partial o/l (bf16) + L=m+log2(l);
// half 0 -> ctx, half 1 -> o1n. merge_k combines exactly.
// key->pos permutation: pos = (k5, k3, k2, k4, k1, k0)
__global__ __launch_bounds__(256, 4) void attn_kernel(const unsigned short* __restrict__ qkv,
                                                      const int* __restrict__ mask,
                                                      unsigned short* __restrict__ ctx,
                                                      unsigned short* __restrict__ o1n,
                                                      float* __restrict__ L0b,
                                                      float* __restrict__ L1b) {
  __shared__ __align__(16) unsigned short Ks[2][64 * 64];  // K [key][d], XOR-swz
  __shared__ __align__(16) unsigned short Vt[2][64 * 64];  // V^T [d][pos], XOR-swz
  __shared__ int tfl[32];
  __shared__ unsigned bmsh;
  const int t = threadIdx.x, lane = t & 63, w = t >> 6;
  const int l15 = lane & 15, l4 = lane >> 4;
  // XCD-chunked swizzle (1536 % 8 == 0, bijective)
  const int u = (blockIdx.x & 7) * 192 + (blockIdx.x >> 3);
  const int half = u & 1;
  const int qt = (u >> 1) & 31;
  const int h = (u >> 6) % 12;
  const int b = u / 768;
  const int kvoff = half * 1024;
  const long rowB = (long)b * SS;

  // ---- per-block mask bitmap: bit kb = "tile kb fully unmasked" ----
  {
    const int* mb = &mask[b * SS + t * 8];
    int4 a0 = *(const int4*)mb;
    int4 a1 = *(const int4*)(mb + 4);
    int allv = (a0.x && a0.y && a0.z && a0.w && a1.x && a1.y && a1.z && a1.w) ? 1 : 0;
    allv &= __shfl_xor(allv, 1);
    allv &= __shfl_xor(allv, 2);
    allv &= __shfl_xor(allv, 4);
    if ((t & 7) == 0) tfl[t >> 3] = allv;
  }
  __syncthreads();
  if (t < 64) {
    int v = (t < 32) ? tfl[t] : 1;
    unsigned long long bl = __ballot(v);
    if (t == 0) bmsh = (unsigned)bl;
  }

  // Q fragment (B operand): lane l15 = q, elems d = ks*32 + l4*8 + j
  bf16x8 aq[2];
#pragma unroll
  for (int ks = 0; ks < 2; ++ks)
    aq[ks] = *(const bf16x8*)&qkv[(rowB + qt * 64 + w * 16 + l15) * QKV_LD +
                                  h * 64 + ks * 32 + l4 * 8];

  // K staging (gload_lds linear dest; XOR swizzle folded into global src col)
  const int krow = w * 8 + (lane >> 3);                          // +p*32
  const int kdo = (((lane & 7) ^ (lane >> 3)) & 7) << 3;         // shorts
  const unsigned short* kgbase = &qkv[(rowB + kvoff + krow) * QKV_LD + 768 + h * 64 + kdo];
  const int kread_swz = (l15 & 7) << 4;

  // V handling
  const unsigned short* vgbase = &qkv[(rowB + kvoff + (t >> 3)) * QKV_LD + 1536 +
                                      h * 64 + (t & 7) * 8];
  const int vd0 = (t & 7) * 8;
  const int vpar = (t >> 3) & 1;
  const int K0 = (t >> 3) & 30;

  uint4 va, vb;
  f32x4 o[4] = {};
  float mrun = -1e30f, lsum = 0.f;

#define VWRITE(buf)                                                             \
  { _Pragma("unroll") for (int p = 0; p < 2; ++p) {                             \
      uint4 vv = p ? vb : va;                                                   \
      unsigned own[4] = {vv.x, vv.y, vv.z, vv.w};                               \
      const int K0p = p * 32 + K0;                                              \
      const int pp = ((K0p & 32) | ((K0p & 12) << 1) | ((K0p & 16) >> 2) | (K0p & 2)) >> 1; \
      _Pragma("unroll") for (int j = 0; j < 4; ++j) {                           \
        unsigned part = __shfl_xor(own[j], 8);                                  \
        unsigned val = vpar ? ((part >> 16) | (own[j] & 0xffff0000u))           \
                            : ((own[j] & 0xffffu) | (part << 16));              \
        int d = vd0 + 2 * j + vpar;                                             \
        int swz = (((2 * j + vpar) ^ (t & 7)) & 7) << 4;                        \
        *(unsigned*)((char*)(buf) + d * 128 + ((pp * 4) ^ swz)) = val;          \
      } } }

  // ---- prologue: stage tile 0 ----
#pragma unroll
  for (int p = 0; p < 2; ++p)
    gload_lds16(kgbase + (long)p * 32 * QKV_LD, (char*)Ks[0] + p * 4096 + w * 1024);
  va = *(const uint4*)(vgbase);
  vb = *(const uint4*)(vgbase + (long)32 * QKV_LD);
  VWRITE(Vt[0]);
  __syncthreads();
  const unsigned bm = bmsh;

  for (int i = 0; i < 16; ++i) {
    const int bi = i & 1;
    const char* Kc = (const char*)Ks[bi];
    const char* Vc = (const char*)Vt[bi];
    // prefetch next tile (K direct-to-LDS, V to regs)
    if (i < 15) {
#pragma unroll
      for (int p = 0; p < 2; ++p)
        gload_lds16(kgbase + ((long)(i + 1) * 64 + p * 32) * QKV_LD,
                    (char*)Ks[bi ^ 1] + p * 4096 + w * 1024);
      va = *(const uint4*)(vgbase + (long)(i + 1) * 64 * QKV_LD);
      vb = *(const uint4*)(vgbase + ((long)(i + 1) * 64 + 32) * QKV_LD);
    }
    // ---- QK^T (swapped): S^T, col=l15=q, key=cg*16+l4*4+r; pre-scaled ----
    f32x4 s[4] = {};
    __builtin_amdgcn_s_setprio(1);
#pragma unroll
    for (int ks = 0; ks < 2; ++ks)
#pragma unroll
      for (int cg = 0; cg < 4; ++cg) {
        bf16x8 ak = *(const bf16x8*)(Kc + (cg * 16 + l15) * 128 +
                                     ((ks * 64 + l4 * 16) ^ kread_swz));
        s[cg] = __builtin_amdgcn_mfma_f32_16x16x32_bf16(ak, aq[ks], s[cg], 0, 0, 0);
      }
    __builtin_amdgcn_s_setprio(0);
    // ---- rare masked-tile path (uniform branch; never taken for all-ones) --
    if (__builtin_expect(!((bm >> (half * 16 + i)) & 1), 0)) {
      const int* mb2 = &mask[b * SS + kvoff + i * 64 + l4 * 4];
#pragma unroll
      for (int cg = 0; cg < 4; ++cg) {
        int4 mm = *(const int4*)(mb2 + cg * 16);
        int mi[4] = {mm.x, mm.y, mm.z, mm.w};
#pragma unroll
        for (int r = 0; r < 4; ++r) s[cg][r] += mi[r] ? 0.f : -1.44269504e9f;
      }
    }
    // ---- online softmax in exp2 domain (per-q stats, q=l15) ----
    float pmax = -3e38f;
#pragma unroll
    for (int cg = 0; cg < 4; ++cg)
#pragma unroll
      for (int r = 0; r < 4; ++r) pmax = fmaxf(pmax, s[cg][r]);
    pmax = fmaxf(pmax, __shfl_xor(pmax, 16));
    pmax = fmaxf(pmax, __shfl_xor(pmax, 32));
    if (!__all(pmax <= mrun + 8.0f)) {   // defer-max (THR=8, exp2 domain)
      float mnew = fmaxf(mrun, pmax);
      float fac = __builtin_amdgcn_exp2f(mrun - mnew);
      lsum *= fac;
#pragma unroll
      for (int mg = 0; mg < 4; ++mg)
#pragma unroll
        for (int r = 0; r < 4; ++r) o[mg][r] *= fac;
      mrun = mnew;
    }
    float sum = 0.f;
#pragma unroll
    for (int cg = 0; cg < 4; ++cg)
#pragma unroll
      for (int r = 0; r < 4; ++r) {
        float p2 = __builtin_amdgcn_exp2f(s[cg][r] - mrun);
        s[cg][r] = p2;
        sum += p2;
      }
    sum += __shfl_xor(sum, 16);
    sum += __shfl_xor(sum, 32);
    lsum += sum;
    // ---- PV: O^T[d][q] += V^T . P^T ; P fragment is lane-local ----
    __builtin_amdgcn_s_setprio(1);
#pragma unroll
    for (int ks = 0; ks < 2; ++ks) {
      union { unsigned uu[4]; bf16x8 b8; } bp;
      bp.uu[0] = cvtpk(s[2 * ks][0], s[2 * ks][1]);
      bp.uu[1] = cvtpk(s[2 * ks][2], s[2 * ks][3]);
      bp.uu[2] = cvtpk(s[2 * ks + 1][0], s[2 * ks + 1][1]);
      bp.uu[3] = cvtpk(s[2 * ks + 1][2], s[2 * ks + 1][3]);
#pragma unroll
      for (int mg = 0; mg < 4; ++mg) {
        const int dv = mg * 16 + l15;
        const int sv = ((dv ^ (dv >> 3)) & 7) << 4;
        bf16x8 av = *(const bf16x8*)(Vc + dv * 128 + ((ks * 64 + l4 * 16) ^ sv));
        o[mg] = __builtin_amdgcn_mfma_f32_16x16x32_bf16(av, bp.b8, o[mg], 0, 0, 0);
      }
    }
    __builtin_amdgcn_s_setprio(0);
    // ---- write next V tile (vreg landed under compute) ----
    if (i < 15) VWRITE(Vt[bi ^ 1]);
    __syncthreads();
  }
  // ---- epilogue: normalized partial + L; O^T regs col q=l15, row d ----
  const float inv = 1.0f / lsum;
  unsigned short* obuf = half ? o1n : ctx;
  const long obase = (rowB + qt * 64 + w * 16 + l15) * DD + h * 64 + l4 * 4;
#pragma unroll
  for (int mg = 0; mg < 4; ++mg) {
    *(unsigned*)&obuf[obase + mg * 16] = cvtpk(o[mg][0] * inv, o[mg][1] * inv);
    *(unsigned*)&obuf[obase + mg * 16 + 2] = cvtpk(o[mg][2] * inv, o[mg][3] * inv);
  }
  if (l4 == 0) {
    float Lv = mrun + __log2f(lsum);
    float* Lb = half ? L1b : L0b;
    Lb[(((b * 12 + h) * 32 + qt) * 64) + w * 16 + l15] = Lv;
  }
#undef VWRITE
}

// ---------------- flash-merge of the two KV-half partials --------------------
__global__ __launch_bounds__(256) void merge_k(const float* __restrict__ L0b,
                                               const float* __restrict__ L1b,
                                               const unsigned short* __restrict__ o1n,
                                               unsigned short* __restrict__ ctx) {
  int gid = blockIdx.x * 256 + threadIdx.x;   // 393216 total
  int row = gid / 96;
  int col = (gid % 96) * 8;
  int h = col >> 6;
  int b = row >> 11, qt = (row & 2047) >> 6, q = row & 63;
  int idx = ((b * 12 + h) * 32 + qt) * 64 + q;
  float l0v = L0b[idx], l1v = L1b[idx];
  float m = fmaxf(l0v, l1v);
  float w0 = __builtin_amdgcn_exp2f(l0v - m), w1 = __builtin_amdgcn_exp2f(l1v - m);
  float s = 1.0f / (w0 + w1);
  w0 *= s; w1 *= s;
  long off = (long)row * DD + col;
  uint4 c0 = *(const uint4*)&ctx[off];
  uint4 c1 = *(const uint4*)&o1n[off];
  unsigned a0[4] = {c0.x, c0.y, c0.z, c0.w};
  unsigned a1[4] = {c1.x, c1.y, c1.z, c1.w};
  unsigned r[4];
#pragma unroll
  for (int j = 0; j < 4; ++j) {
    float lo0 = __uint_as_float(a0[j] << 16), hi0 = __uint_as_float(a0[j] & 0xffff0000u);
    float lo1 = __uint_as_float(a1[j] << 16), hi1 = __uint_as_float(a1[j] & 0xffff0000u);
    r[j] = cvtpk(w0 * lo0 + w1 * lo1, w0 * hi0 + w1 * hi1);
  }
  *(uint4*)&ctx[off] = make_uint4(r[0], r[1], r[2], r[3]);
}

// ---------------- workspace layout (bytes) ----------------
static const size_t OFF_WQKV = 0;          // 2304*768*2  = 3538944 (L0/L1 reuse post-QKV)
static const size_t OFF_WO = 3538944;      // 768*768*2   = 1179648
static const size_t OFF_W1 = 4718592;      // 2048*768*2  = 3145728
static const size_t OFF_W2 = 7864320;      // 768*2048*2  = 3145728
static const size_t OFF_BQKV = 11010048;   // 2304*4
static const size_t OFF_N = 11019264;      // 4096*768*2  (reused: o1n partial, then n2)
static const size_t OFF_QKV = 17310720;    // 4096*2304*2 (reused for h)
static const size_t OFF_CTX = 36185088;    // 4096*768*2
static const size_t OFF_X1 = 42476544;     // 4096*768*4
// total = 55059456 bytes

extern "C" void kernel_launch(void* const* d_in, const int* in_sizes, int n_in,
                              void* d_out, int out_size, void* d_ws, size_t ws_size,
                              hipStream_t stream) {
  (void)in_sizes; (void)n_in; (void)out_size; (void)ws_size;
  const float* x = (const float*)d_in[0];
  const int* mask = (const int*)d_in[1];
  const float* Wq = (const float*)d_in[2];
  const float* bq = (const float*)d_in[3];
  const float* Wk = (const float*)d_in[4];
  const float* bk = (const float*)d_in[5];
  const float* Wv = (const float*)d_in[6];
  const float* bv = (const float*)d_in[7];
  const float* Wo = (const float*)d_in[8];
  const float* bo = (const float*)d_in[9];
  const float* W1 = (const float*)d_in[10];
  const float* b1 = (const float*)d_in[11];
  const float* W2 = (const float*)d_in[12];
  const float* b2 = (const float*)d_in[13];
  const float* alpha = (const float*)d_in[14];
  const float* beta = (const float*)d_in[15];

  char* ws = (char*)d_ws;
  unsigned short* wqkv = (unsigned short*)(ws + OFF_WQKV);
  unsigned short* wo_b = (unsigned short*)(ws + OFF_WO);
  unsigned short* w1_b = (unsigned short*)(ws + OFF_W1);
  unsigned short* w2_b = (unsigned short*)(ws + OFF_W2);
  float* bqkv = (float*)(ws + OFF_BQKV);
  unsigned short* n_b = (unsigned short*)(ws + OFF_N);
  unsigned short* qkv_b = (unsigned short*)(ws + OFF_QKV);
  unsigned short* h_b = qkv_b;  // reuse after attention
  unsigned short* ctx_b = (unsigned short*)(ws + OFF_CTX);
  float* x1_f = (float*)(ws + OFF_X1);
  float* out_f = (float*)d_out;
  // attention partials reuse dead regions during the attn..merge window:
  float* L0b = (float*)(ws + OFF_WQKV);              // 196608 B
  float* L1b = (float*)(ws + OFF_WQKV + 262144);     // 196608 B (within wqkv)
  unsigned short* o1n = n_b;                         // 6291456 B

  // weights->bf16 + bias concat + LN1 in one launch (5377 cvt/bias + 1024 LN)
  pre_k<<<6401, 256, 0, stream>>>(Wq, Wk, Wv, Wo, W1, W2, bq, bk, bv,
                                  x, alpha, beta, wqkv, wo_b, w1_b, w2_b, bqkv, n_b);
  // fused QKV GEMM: [4096,768] x [2304,768]^T -> [4096,2304] bf16, Q pre-scaled
  gemm_bt<128, false, false, true, true><<<dim3(18, 32), 256, 0, stream>>>(
      n_b, wqkv, bqkv, nullptr, qkv_b, BSR, QKV_LD, DD);
  // attention: split-KV across 1536 blocks, then exact flash-merge
  attn_kernel<<<1536, 256, 0, stream>>>(qkv_b, mask, ctx_b, o1n, L0b, L1b);
  merge_k<<<1536, 256, 0, stream>>>(L0b, L1b, o1n, ctx_b);
  // Wo GEMM + residual(x) -> x1 fp32 (BN=64: 384 blocks)
  gemm_bt<64, false, true, false, false><<<dim3(12, 32), 256, 0, stream>>>(
      ctx_b, wo_b, bo, x, x1_f, BSR, DD, DD);
  // LN2
  layernorm_k<<<1024, 256, 0, stream>>>(x1_f, alpha, beta, n_b);
  // FFN1 + relu -> h bf16
  gemm_bt<128, true, false, true, false><<<dim3(16, 32), 256, 0, stream>>>(
      n_b, w1_b, b1, nullptr, h_b, BSR, DFFF, DD);
  // FFN2 + residual(x1) -> out fp32 (BN=64: 384 blocks)
  gemm_bt<64, false, true, false, false><<<dim3(12, 32), 256, 0, stream>>>(
      h_b, w2_b, b2, x1_f, out_f, BSR, DD, DFFF);
}

// Round 8
// 196.928 us; speedup vs baseline: 1.0446x; 1.0261x over previous
//
#include <hip/hip_runtime.h>

// EncoderLayer: pre-norm MHA + FFN, B=2 S=2048 D=768 H=12 DFF=2048, fp32 I/O,
// bf16 MFMA internals. Pipeline:
//   pre (weights->bf16 + bias concat + LN1), QKV-GEMM(fused N=2304, Q pre-scaled),
//   flash-attn (split-KV across blocks) + merge, Wo-GEMM+res, LN2, FFN1+relu,
//   FFN2+res -> d_out
#define SS   2048
#define DD   768
#define HH   12
#define DFFF 2048
#define BSR  4096      // B*S
#define QKV_LD 2304

typedef __attribute__((ext_vector_type(8))) short bf16x8;
typedef __attribute__((ext_vector_type(4))) float f32x4;

__device__ __forceinline__ unsigned short f2b(float f) {
  union { float f; unsigned u; } x; x.f = f;
  unsigned r = (x.u + 0x7FFFu + ((x.u >> 16) & 1u)) >> 16;
  return (unsigned short)r;
}

__device__ __forceinline__ unsigned cvtpk(float lo, float hi) {
  unsigned r;
  asm("v_cvt_pk_bf16_f32 %0, %1, %2" : "=v"(r) : "v"(lo), "v"(hi));
  return r;
}

__device__ __forceinline__ void gload_lds16(const void* g, void* l) {
  __builtin_amdgcn_global_load_lds(
      (const __attribute__((address_space(1))) unsigned int*)g,
      (__attribute__((address_space(3))) unsigned int*)l,
      16, 0, 0);
}

// ---------------- LayerNorm row (torch semantics: ddof=1, eps on std) -------
__device__ __forceinline__ void ln_row(const float* __restrict__ xr,
                                       const float* __restrict__ alpha,
                                       const float* __restrict__ beta,
                                       unsigned short* __restrict__ orow, int lane) {
  float4 v[3];
#pragma unroll
  for (int g = 0; g < 3; ++g) v[g] = *(const float4*)&xr[lane * 12 + g * 4];
  float sum = 0.f;
#pragma unroll
  for (int g = 0; g < 3; ++g) sum += v[g].x + v[g].y + v[g].z + v[g].w;
#pragma unroll
  for (int off = 1; off < 64; off <<= 1) sum += __shfl_xor(sum, off);
  float mu = sum * (1.0f / 768.0f);
  float ss = 0.f;
#pragma unroll
  for (int g = 0; g < 3; ++g) {
    float a0 = v[g].x - mu, a1 = v[g].y - mu, a2 = v[g].z - mu, a3 = v[g].w - mu;
    ss += a0 * a0 + a1 * a1 + a2 * a2 + a3 * a3;
  }
#pragma unroll
  for (int off = 1; off < 64; off <<= 1) ss += __shfl_xor(ss, off);
  float sd = sqrtf(ss * (1.0f / 767.0f));
  float inv = 1.0f / (sd + 1e-6f);
#pragma unroll
  for (int g = 0; g < 3; ++g) {
    float4 al = *(const float4*)&alpha[lane * 12 + g * 4];
    float4 be = *(const float4*)&beta[lane * 12 + g * 4];
    uint2 pk;
    pk.x = cvtpk(al.x * (v[g].x - mu) * inv + be.x, al.y * (v[g].y - mu) * inv + be.y);
    pk.y = cvtpk(al.z * (v[g].z - mu) * inv + be.z, al.w * (v[g].w - mu) * inv + be.w);
    *(uint2*)&orow[lane * 12 + g * 4] = pk;
  }
}

// ------- merged: weight fp32->bf16 + bias concat + LN1 (one launch) ---------
__global__ __launch_bounds__(256) void pre_k(const float* __restrict__ Wq,
                                             const float* __restrict__ Wk,
                                             const float* __restrict__ Wv,
                                             const float* __restrict__ Wo,
                                             const float* __restrict__ W1,
                                             const float* __restrict__ W2,
                                             const float* __restrict__ bq,
                                             const float* __restrict__ bk,
                                             const float* __restrict__ bv,
                                             const float* __restrict__ x,
                                             const float* __restrict__ alpha,
                                             const float* __restrict__ beta,
                                             unsigned short* __restrict__ wqkv,
                                             unsigned short* __restrict__ wo_b,
                                             unsigned short* __restrict__ w1_b,
                                             unsigned short* __restrict__ w2_b,
                                             float* __restrict__ bqkv,
                                             unsigned short* __restrict__ n_b) {
  const int blk = blockIdx.x;
  const float* src;
  unsigned short* dst;
  long off;
  if (blk < 1728) {            // Wq/Wk/Wv -> wqkv rows [0,2304)
    int r = blk / 576;
    src = r == 0 ? Wq : r == 1 ? Wk : Wv;
    dst = wqkv + (long)r * 589824;
    off = (long)(blk - r * 576) * 1024 + threadIdx.x * 4;
  } else if (blk < 2304) {
    src = Wo; dst = wo_b; off = (long)(blk - 1728) * 1024 + threadIdx.x * 4;
  } else if (blk < 3840) {
    src = W1; dst = w1_b; off = (long)(blk - 2304) * 1024 + threadIdx.x * 4;
  } else if (blk < 5376) {
    src = W2; dst = w2_b; off = (long)(blk - 3840) * 1024 + threadIdx.x * 4;
  } else if (blk == 5376) {    // bias concat
    for (int k = threadIdx.x; k < 2304; k += 256)
      bqkv[k] = k < 768 ? bq[k] : k < 1536 ? bk[k - 768] : bv[k - 1536];
    return;
  } else {                     // LN1: 4 rows per block
    int row = (blk - 5377) * 4 + (threadIdx.x >> 6);
    ln_row(x + (long)row * DD, alpha, beta, n_b + (long)row * DD, threadIdx.x & 63);
    return;
  }
  float4 v = *(const float4*)&src[off];
  uint2 pk;
  pk.x = cvtpk(v.x, v.y);
  pk.y = cvtpk(v.z, v.w);
  *(uint2*)&dst[off] = pk;
}

// ---------------- LN2 standalone ----------------
__global__ __launch_bounds__(256) void layernorm_k(const float* __restrict__ x,
                                                   const float* __restrict__ alpha,
                                                   const float* __restrict__ beta,
                                                   unsigned short* __restrict__ outb) {
  int row = blockIdx.x * 4 + (threadIdx.x >> 6);
  ln_row(x + (long)row * DD, alpha, beta, outb + (long)row * DD, threadIdx.x & 63);
}

// ---------------- bf16 GEMM: C[M,N] = A[M,K] * W[N,K]^T (+bias,+res,relu) ----
// 128xBN tile, BK=64, 4 waves, global_load_lds staging (m97 structure).
// XCD-chunked block swizzle (requires nwg % 8 == 0) for A-panel L2 locality.
// QSC: scale cols<768 by 0.125*log2(e) (Q pre-scale for exp2-domain attn).
template <int BN, bool RELU, bool RES, bool OUTB, bool QSC>
__global__ __launch_bounds__(256, BN == 64 ? 4 : 2)
void gemm_bt(const unsigned short* __restrict__ A,
             const unsigned short* __restrict__ W,
             const float* __restrict__ bias,
             const float* __restrict__ res,
             void* __restrict__ outp,
             int M, int N, int K) {
  __shared__ __align__(16) unsigned short As[128 * 64];
  __shared__ __align__(16) unsigned short Bs[BN * 64];
  constexpr int NF = BN / 32;   // 16-wide col frags per wave
  const int t = threadIdx.x;
  const int lane = t & 63;
  const int w = t >> 6;
  const int wr = w >> 1, wc = w & 1;
  const int l15 = lane & 15, l4 = lane >> 4;
  // XCD-chunked swizzle: contiguous chunk of blocks (sharing A-panels) per XCD
  const int nwg = gridDim.x * gridDim.y;
  const int lin = blockIdx.y * gridDim.x + blockIdx.x;
  const int u2 = (lin & 7) * (nwg >> 3) + (lin >> 3);
  const long brow = (long)(u2 / gridDim.x) * 128;
  const long bcol = (long)(u2 % gridDim.x) * BN;
  f32x4 acc[4][NF] = {};
  const int r0 = t >> 3;        // 0..31
  const int c8 = (t & 7) * 8;   // 0..56

  for (int k0 = 0; k0 < K; k0 += 64) {
    __syncthreads();
#pragma unroll
    for (int p = 0; p < 4; ++p)
      gload_lds16(&A[(brow + p * 32 + r0) * (long)K + k0 + c8],
                  (char*)As + p * 4096 + w * 1024);
#pragma unroll
    for (int p = 0; p < BN / 32; ++p)
      gload_lds16(&W[(bcol + p * 32 + r0) * (long)K + k0 + c8],
                  (char*)Bs + p * 4096 + w * 1024);
    __syncthreads();
#pragma unroll
    for (int ks = 0; ks < 2; ++ks) {
      bf16x8 a[4], b[NF];
#pragma unroll
      for (int m = 0; m < 4; ++m)
        a[m] = *(const bf16x8*)&As[(wr * 64 + m * 16 + l15) * 64 + ks * 32 + l4 * 8];
#pragma unroll
      for (int n = 0; n < NF; ++n)
        b[n] = *(const bf16x8*)&Bs[(wc * (BN / 2) + n * 16 + l15) * 64 + ks * 32 + l4 * 8];
#pragma unroll
      for (int m = 0; m < 4; ++m)
#pragma unroll
        for (int n = 0; n < NF; ++n)
          acc[m][n] = __builtin_amdgcn_mfma_f32_16x16x32_bf16(a[m], b[n], acc[m][n], 0, 0, 0);
    }
  }
#pragma unroll
  for (int n = 0; n < NF; ++n) {
    const long col = bcol + wc * (BN / 2) + n * 16 + l15;
    const float bv = bias[col];
    const float sc = (QSC && col < 768) ? 0.18033688f : 1.0f;
#pragma unroll
    for (int m = 0; m < 4; ++m) {
      const long row0 = brow + wr * 64 + m * 16 + l4 * 4;
#pragma unroll
      for (int r = 0; r < 4; ++r) {
        float v = acc[m][n][r] + bv;
        if (RELU) v = fmaxf(v, 0.0f);
        if (QSC) v *= sc;
        long o = (row0 + r) * (long)N + col;
        if (RES) v += res[o];
        if (OUTB) ((unsigned short*)outp)[o] = f2b(v);
        else ((float*)outp)[o] = v;
      }
    }
  }
}

// ---------------- flash attention v8: split-KV across blocks ----------------
// Grid 1536 = (b,h,qt,half); 256 threads, 4 waves, LDS exactly 32 KB ->
// 5 blocks/CU. Swapped QK^T (Q pre-scaled), K via global_load_lds (dbuf,
// XOR-swz), V transposed into key-permuted LDS (lane-local P), exp2 softmax,
// defer-max, v_perm transpose. Mask bitmap scratch aliased onto Vt[0];
// each wave ballots its own bitmap. Epilogue: normalized partial o/l (bf16)
// + L=m+log2(l); half 0 -> ctx, half 1 -> o1n. merge_k combines exactly.
// key->pos permutation: pos = (k5, k3, k2, k4, k1, k0)
__global__ __launch_bounds__(256, 5) void attn_kernel(const unsigned short* __restrict__ qkv,
                                                      const int* __restrict__ mask,
                                                      unsigned short* __restrict__ ctx,
                                                      unsigned short* __restrict__ o1n,
                                                      float* __restrict__ L0b,
                                                      float* __restrict__ L1b) {
  __shared__ __align__(16) unsigned short Ks[2][64 * 64];  // K [key][d], XOR-swz
  __shared__ __align__(16) unsigned short Vt[2][64 * 64];  // V^T [d][pos], XOR-swz
  const int t = threadIdx.x, lane = t & 63, w = t >> 6;
  const int l15 = lane & 15, l4 = lane >> 4;
  // XCD-chunked swizzle (1536 % 8 == 0, bijective)
  const int u = (blockIdx.x & 7) * 192 + (blockIdx.x >> 3);
  const int half = u & 1;
  const int qt = (u >> 1) & 31;
  const int h = (u >> 6) % 12;
  const int b = u / 768;
  const int kvoff = half * 1024;
  const long rowB = (long)b * SS;

  // ---- mask bitmap (scratch aliased onto Vt[0]; Vt staged only later) ----
  unsigned bm;
  {
    int* tfl = (int*)&Vt[0][0];
    const int* mb = &mask[b * SS + t * 8];
    int4 a0 = *(const int4*)mb;
    int4 a1 = *(const int4*)(mb + 4);
    int allv = (a0.x && a0.y && a0.z && a0.w && a1.x && a1.y && a1.z && a1.w) ? 1 : 0;
    allv &= __shfl_xor(allv, 1);
    allv &= __shfl_xor(allv, 2);
    allv &= __shfl_xor(allv, 4);
    if ((t & 7) == 0) tfl[t >> 3] = allv;
    __syncthreads();
    int vv = (lane < 32) ? tfl[lane] : 1;
    bm = (unsigned)__ballot(vv);   // per-wave; low 32 bits = tiles 0..31
    __syncthreads();               // scratch dead before Vt[0] is staged
  }

  // Q fragment (B operand): lane l15 = q, elems d = ks*32 + l4*8 + j
  bf16x8 aq[2];
#pragma unroll
  for (int ks = 0; ks < 2; ++ks)
    aq[ks] = *(const bf16x8*)&qkv[(rowB + qt * 64 + w * 16 + l15) * QKV_LD +
                                  h * 64 + ks * 32 + l4 * 8];

  // K staging (gload_lds linear dest; XOR swizzle folded into global src col)
  const int krow = w * 8 + (lane >> 3);                          // +p*32
  const int kdo = (((lane & 7) ^ (lane >> 3)) & 7) << 3;         // shorts
  const unsigned short* kgbase = &qkv[(rowB + kvoff + krow) * QKV_LD + 768 + h * 64 + kdo];
  const int kread_swz = (l15 & 7) << 4;

  // V handling
  const unsigned short* vgbase = &qkv[(rowB + kvoff + (t >> 3)) * QKV_LD + 1536 +
                                      h * 64 + (t & 7) * 8];
  const int vd0 = (t & 7) * 8;
  const int vpar = (t >> 3) & 1;
  const int K0 = (t >> 3) & 30;
  const unsigned psel = vpar ? 0x07060302u : 0x01000504u;  // v_perm selector

  uint4 va, vb;
  f32x4 o[4] = {};
  float mrun = -1e30f, lsum = 0.f;

#define VWRITE(buf)                                                             \
  { _Pragma("unroll") for (int p = 0; p < 2; ++p) {                             \
      uint4 vv = p ? vb : va;                                                   \
      unsigned own[4] = {vv.x, vv.y, vv.z, vv.w};                               \
      const int K0p = p * 32 + K0;                                              \
      const int pp = ((K0p & 32) | ((K0p & 12) << 1) | ((K0p & 16) >> 2) | (K0p & 2)) >> 1; \
      _Pragma("unroll") for (int j = 0; j < 4; ++j) {                           \
        unsigned part = __shfl_xor(own[j], 8);                                  \
        unsigned val = __builtin_amdgcn_perm(own[j], part, psel);               \
        int d = vd0 + 2 * j + vpar;                                             \
        int swz = (((2 * j + vpar) ^ (t & 7)) & 7) << 4;                        \
        *(unsigned*)((char*)(buf) + d * 128 + ((pp * 4) ^ swz)) = val;          \
      } } }

  // ---- prologue: stage tile 0 ----
#pragma unroll
  for (int p = 0; p < 2; ++p)
    gload_lds16(kgbase + (long)p * 32 * QKV_LD, (char*)Ks[0] + p * 4096 + w * 1024);
  va = *(const uint4*)(vgbase);
  vb = *(const uint4*)(vgbase + (long)32 * QKV_LD);
  VWRITE(Vt[0]);
  __syncthreads();

  for (int i = 0; i < 16; ++i) {
    const int bi = i & 1;
    const char* Kc = (const char*)Ks[bi];
    const char* Vc = (const char*)Vt[bi];
    // prefetch next tile (K direct-to-LDS, V to regs)
    if (i < 15) {
#pragma unroll
      for (int p = 0; p < 2; ++p)
        gload_lds16(kgbase + ((long)(i + 1) * 64 + p * 32) * QKV_LD,
                    (char*)Ks[bi ^ 1] + p * 4096 + w * 1024);
      va = *(const uint4*)(vgbase + (long)(i + 1) * 64 * QKV_LD);
      vb = *(const uint4*)(vgbase + ((long)(i + 1) * 64 + 32) * QKV_LD);
    }
    // ---- QK^T (swapped): S^T, col=l15=q, key=cg*16+l4*4+r; pre-scaled ----
    f32x4 s[4] = {};
    __builtin_amdgcn_s_setprio(1);
#pragma unroll
    for (int ks = 0; ks < 2; ++ks)
#pragma unroll
      for (int cg = 0; cg < 4; ++cg) {
        bf16x8 ak = *(const bf16x8*)(Kc + (cg * 16 + l15) * 128 +
                                     ((ks * 64 + l4 * 16) ^ kread_swz));
        s[cg] = __builtin_amdgcn_mfma_f32_16x16x32_bf16(ak, aq[ks], s[cg], 0, 0, 0);
      }
    __builtin_amdgcn_s_setprio(0);
    // ---- rare masked-tile path (uniform branch; never taken for all-ones) --
    if (__builtin_expect(!((bm >> (half * 16 + i)) & 1), 0)) {
      const int* mb2 = &mask[b * SS + kvoff + i * 64 + l4 * 4];
#pragma unroll
      for (int cg = 0; cg < 4; ++cg) {
        int4 mm = *(const int4*)(mb2 + cg * 16);
        int mi[4] = {mm.x, mm.y, mm.z, mm.w};
#pragma unroll
        for (int r = 0; r < 4; ++r) s[cg][r] += mi[r] ? 0.f : -1.44269504e9f;
      }
    }
    // ---- online softmax in exp2 domain (per-q stats, q=l15) ----
    // max3-friendly reduction tree (clang fuses fmax triples to v_max3_f32)
    float t0 = fmaxf(fmaxf(s[0][0], s[0][1]), s[0][2]);
    float t1 = fmaxf(fmaxf(s[0][3], s[1][0]), s[1][1]);
    float t2 = fmaxf(fmaxf(s[1][2], s[1][3]), s[2][0]);
    float t3 = fmaxf(fmaxf(s[2][1], s[2][2]), s[2][3]);
    float t4 = fmaxf(fmaxf(s[3][0], s[3][1]), s[3][2]);
    float t5 = fmaxf(fmaxf(t0, t1), t2);
    float t6 = fmaxf(fmaxf(t3, t4), s[3][3]);
    float pmax = fmaxf(t5, t6);
    pmax = fmaxf(pmax, __shfl_xor(pmax, 16));
    pmax = fmaxf(pmax, __shfl_xor(pmax, 32));
    if (!__all(pmax <= mrun + 8.0f)) {   // defer-max (THR=8, exp2 domain)
      float mnew = fmaxf(mrun, pmax);
      float fac = __builtin_amdgcn_exp2f(mrun - mnew);
      lsum *= fac;
#pragma unroll
      for (int mg = 0; mg < 4; ++mg)
#pragma unroll
        for (int r = 0; r < 4; ++r) o[mg][r] *= fac;
      mrun = mnew;
    }
    float sum = 0.f;
#pragma unroll
    for (int cg = 0; cg < 4; ++cg)
#pragma unroll
      for (int r = 0; r < 4; ++r) {
        float p2 = __builtin_amdgcn_exp2f(s[cg][r] - mrun);
        s[cg][r] = p2;
        sum += p2;
      }
    sum += __shfl_xor(sum, 16);
    sum += __shfl_xor(sum, 32);
    lsum += sum;
    // ---- PV: O^T[d][q] += V^T . P^T ; P fragment is lane-local ----
    __builtin_amdgcn_s_setprio(1);
#pragma unroll
    for (int ks = 0; ks < 2; ++ks) {
      union { unsigned uu[4]; bf16x8 b8; } bp;
      bp.uu[0] = cvtpk(s[2 * ks][0], s[2 * ks][1]);
      bp.uu[1] = cvtpk(s[2 * ks][2], s[2 * ks][3]);
      bp.uu[2] = cvtpk(s[2 * ks + 1][0], s[2 * ks + 1][1]);
      bp.uu[3] = cvtpk(s[2 * ks + 1][2], s[2 * ks + 1][3]);
#pragma unroll
      for (int mg = 0; mg < 4; ++mg) {
        const int dv = mg * 16 + l15;
        const int sv = ((dv ^ (dv >> 3)) & 7) << 4;
        bf16x8 av = *(const bf16x8*)(Vc + dv * 128 + ((ks * 64 + l4 * 16) ^ sv));
        o[mg] = __builtin_amdgcn_mfma_f32_16x16x32_bf16(av, bp.b8, o[mg], 0, 0, 0);
      }
    }
    __builtin_amdgcn_s_setprio(0);
    // ---- write next V tile (vreg landed under compute) ----
    if (i < 15) VWRITE(Vt[bi ^ 1]);
    __syncthreads();
  }
  // ---- epilogue: normalized partial + L; O^T regs col q=l15, row d ----
  const float inv = 1.0f / lsum;
  unsigned short* obuf = half ? o1n : ctx;
  const long obase = (rowB + qt * 64 + w * 16 + l15) * DD + h * 64 + l4 * 4;
#pragma unroll
  for (int mg = 0; mg < 4; ++mg) {
    *(unsigned*)&obuf[obase + mg * 16] = cvtpk(o[mg][0] * inv, o[mg][1] * inv);
    *(unsigned*)&obuf[obase + mg * 16 + 2] = cvtpk(o[mg][2] * inv, o[mg][3] * inv);
  }
  if (l4 == 0) {
    float Lv = mrun + __log2f(lsum);
    float* Lb = half ? L1b : L0b;
    Lb[(((b * 12 + h) * 32 + qt) * 64) + w * 16 + l15] = Lv;
  }
#undef VWRITE
}

// ---------------- flash-merge of the two KV-half partials --------------------
__global__ __launch_bounds__(256) void merge_k(const float* __restrict__ L0b,
                                               const float* __restrict__ L1b,
                                               const unsigned short* __restrict__ o1n,
                                               unsigned short* __restrict__ ctx) {
  int gid = blockIdx.x * 256 + threadIdx.x;   // 393216 total
  int row = gid / 96;
  int col = (gid % 96) * 8;
  int h = col >> 6;
  int b = row >> 11, qt = (row & 2047) >> 6, q = row & 63;
  int idx = ((b * 12 + h) * 32 + qt) * 64 + q;
  float l0v = L0b[idx], l1v = L1b[idx];
  float m = fmaxf(l0v, l1v);
  float w0 = __builtin_amdgcn_exp2f(l0v - m), w1 = __builtin_amdgcn_exp2f(l1v - m);
  float s = 1.0f / (w0 + w1);
  w0 *= s; w1 *= s;
  long off = (long)row * DD + col;
  uint4 c0 = *(const uint4*)&ctx[off];
  uint4 c1 = *(const uint4*)&o1n[off];
  unsigned a0[4] = {c0.x, c0.y, c0.z, c0.w};
  unsigned a1[4] = {c1.x, c1.y, c1.z, c1.w};
  unsigned r[4];
#pragma unroll
  for (int j = 0; j < 4; ++j) {
    float lo0 = __uint_as_float(a0[j] << 16), hi0 = __uint_as_float(a0[j] & 0xffff0000u);
    float lo1 = __uint_as_float(a1[j] << 16), hi1 = __uint_as_float(a1[j] & 0xffff0000u);
    r[j] = cvtpk(w0 * lo0 + w1 * lo1, w0 * hi0 + w1 * hi1);
  }
  *(uint4*)&ctx[off] = make_uint4(r[0], r[1], r[2], r[3]);
}

// ---------------- workspace layout (bytes) ----------------
static const size_t OFF_WQKV = 0;          // 2304*768*2  = 3538944 (L0/L1 reuse post-QKV)
static const size_t OFF_WO = 3538944;      // 768*768*2   = 1179648
static const size_t OFF_W1 = 4718592;      // 2048*768*2  = 3145728
static const size_t OFF_W2 = 7864320;      // 768*2048*2  = 3145728
static const size_t OFF_BQKV = 11010048;   // 2304*4
static const size_t OFF_N = 11019264;      // 4096*768*2  (reused: o1n partial, then n2)
static const size_t OFF_QKV = 17310720;    // 4096*2304*2 (reused for h)
static const size_t OFF_CTX = 36185088;    // 4096*768*2
static const size_t OFF_X1 = 42476544;     // 4096*768*4
// total = 55059456 bytes

extern "C" void kernel_launch(void* const* d_in, const int* in_sizes, int n_in,
                              void* d_out, int out_size, void* d_ws, size_t ws_size,
                              hipStream_t stream) {
  (void)in_sizes; (void)n_in; (void)out_size; (void)ws_size;
  const float* x = (const float*)d_in[0];
  const int* mask = (const int*)d_in[1];
  const float* Wq = (const float*)d_in[2];
  const float* bq = (const float*)d_in[3];
  const float* Wk = (const float*)d_in[4];
  const float* bk = (const float*)d_in[5];
  const float* Wv = (const float*)d_in[6];
  const float* bv = (const float*)d_in[7];
  const float* Wo = (const float*)d_in[8];
  const float* bo = (const float*)d_in[9];
  const float* W1 = (const float*)d_in[10];
  const float* b1 = (const float*)d_in[11];
  const float* W2 = (const float*)d_in[12];
  const float* b2 = (const float*)d_in[13];
  const float* alpha = (const float*)d_in[14];
  const float* beta = (const float*)d_in[15];

  char* ws = (char*)d_ws;
  unsigned short* wqkv = (unsigned short*)(ws + OFF_WQKV);
  unsigned short* wo_b = (unsigned short*)(ws + OFF_WO);
  unsigned short* w1_b = (unsigned short*)(ws + OFF_W1);
  unsigned short* w2_b = (unsigned short*)(ws + OFF_W2);
  float* bqkv = (float*)(ws + OFF_BQKV);
  unsigned short* n_b = (unsigned short*)(ws + OFF_N);
  unsigned short* qkv_b = (unsigned short*)(ws + OFF_QKV);
  unsigned short* h_b = qkv_b;  // reuse after attention
  unsigned short* ctx_b = (unsigned short*)(ws + OFF_CTX);
  float* x1_f = (float*)(ws + OFF_X1);
  float* out_f = (float*)d_out;
  // attention partials reuse dead regions during the attn..merge window:
  float* L0b = (float*)(ws + OFF_WQKV);              // 196608 B
  float* L1b = (float*)(ws + OFF_WQKV + 262144);     // 196608 B (within wqkv)
  unsigned short* o1n = n_b;                         // 6291456 B

  // weights->bf16 + bias concat + LN1 in one launch (5377 cvt/bias + 1024 LN)
  pre_k<<<6401, 256, 0, stream>>>(Wq, Wk, Wv, Wo, W1, W2, bq, bk, bv,
                                  x, alpha, beta, wqkv, wo_b, w1_b, w2_b, bqkv, n_b);
  // fused QKV GEMM: [4096,768] x [2304,768]^T -> [4096,2304] bf16, Q pre-scaled
  gemm_bt<128, false, false, true, true><<<dim3(18, 32), 256, 0, stream>>>(
      n_b, wqkv, bqkv, nullptr, qkv_b, BSR, QKV_LD, DD);
  // attention: split-KV across 1536 blocks, then exact flash-merge
  attn_kernel<<<1536, 256, 0, stream>>>(qkv_b, mask, ctx_b, o1n, L0b, L1b);
  merge_k<<<1536, 256, 0, stream>>>(L0b, L1b, o1n, ctx_b);
  // Wo GEMM + residual(x) -> x1 fp32 (BN=64: 384 blocks)
  gemm_bt<64, false, true, false, false><<<dim3(12, 32), 256, 0, stream>>>(
      ctx_b, wo_b, bo, x, x1_f, BSR, DD, DD);
  // LN2
  layernorm_k<<<1024, 256, 0, stream>>>(x1_f, alpha, beta, n_b);
  // FFN1 + relu -> h bf16
  gemm_bt<128, true, false, true, false><<<dim3(16, 32), 256, 0, stream>>>(
      n_b, w1_b, b1, nullptr, h_b, BSR, DFFF, DD);
  // FFN2 + residual(x1) -> out fp32 (BN=64: 384 blocks)
  gemm_bt<64, false, true, false, false><<<dim3(12, 32), 256, 0, stream>>>(
      h_b, w2_b, b2, x1_f, out_f, BSR, DD, DFFF);
}

// Round 10
// 186.661 us; speedup vs baseline: 1.1021x; 1.0550x over previous
//
#include <hip/hip_runtime.h>

// EncoderLayer: pre-norm MHA + FFN, B=2 S=2048 D=768 H=12 DFF=2048, fp32 I/O,
// bf16 MFMA internals. Pipeline:
//   pre (weights->bf16 + bias concat + LN1), QKV-GEMM(fused N=2304, Q pre-scaled),
//   flash-attn (one block per (b,h,qt), full KV), Wo-GEMM+res, LN2, FFN1+relu,
//   FFN2+res -> d_out
#define SS   2048
#define DD   768
#define HH   12
#define DFFF 2048
#define BSR  4096      // B*S
#define QKV_LD 2304

typedef __attribute__((ext_vector_type(8))) short bf16x8;
typedef __attribute__((ext_vector_type(4))) float f32x4;

__device__ __forceinline__ unsigned short f2b(float f) {
  union { float f; unsigned u; } x; x.f = f;
  unsigned r = (x.u + 0x7FFFu + ((x.u >> 16) & 1u)) >> 16;
  return (unsigned short)r;
}

__device__ __forceinline__ unsigned cvtpk(float lo, float hi) {
  unsigned r;
  asm("v_cvt_pk_bf16_f32 %0, %1, %2" : "=v"(r) : "v"(lo), "v"(hi));
  return r;
}

__device__ __forceinline__ void gload_lds16(const void* g, void* l) {
  __builtin_amdgcn_global_load_lds(
      (const __attribute__((address_space(1))) unsigned int*)g,
      (__attribute__((address_space(3))) unsigned int*)l,
      16, 0, 0);
}

// ---------------- LayerNorm row (torch semantics: ddof=1, eps on std) -------
__device__ __forceinline__ void ln_row(const float* __restrict__ xr,
                                       const float* __restrict__ alpha,
                                       const float* __restrict__ beta,
                                       unsigned short* __restrict__ orow, int lane) {
  float4 v[3];
#pragma unroll
  for (int g = 0; g < 3; ++g) v[g] = *(const float4*)&xr[lane * 12 + g * 4];
  float sum = 0.f;
#pragma unroll
  for (int g = 0; g < 3; ++g) sum += v[g].x + v[g].y + v[g].z + v[g].w;
#pragma unroll
  for (int off = 1; off < 64; off <<= 1) sum += __shfl_xor(sum, off);
  float mu = sum * (1.0f / 768.0f);
  float ss = 0.f;
#pragma unroll
  for (int g = 0; g < 3; ++g) {
    float a0 = v[g].x - mu, a1 = v[g].y - mu, a2 = v[g].z - mu, a3 = v[g].w - mu;
    ss += a0 * a0 + a1 * a1 + a2 * a2 + a3 * a3;
  }
#pragma unroll
  for (int off = 1; off < 64; off <<= 1) ss += __shfl_xor(ss, off);
  float sd = sqrtf(ss * (1.0f / 767.0f));
  float inv = 1.0f / (sd + 1e-6f);
#pragma unroll
  for (int g = 0; g < 3; ++g) {
    float4 al = *(const float4*)&alpha[lane * 12 + g * 4];
    float4 be = *(const float4*)&beta[lane * 12 + g * 4];
    uint2 pk;
    pk.x = cvtpk(al.x * (v[g].x - mu) * inv + be.x, al.y * (v[g].y - mu) * inv + be.y);
    pk.y = cvtpk(al.z * (v[g].z - mu) * inv + be.z, al.w * (v[g].w - mu) * inv + be.w);
    *(uint2*)&orow[lane * 12 + g * 4] = pk;
  }
}

// ------- merged: weight fp32->bf16 + bias concat + LN1 (one launch) ---------
__global__ __launch_bounds__(256) void pre_k(const float* __restrict__ Wq,
                                             const float* __restrict__ Wk,
                                             const float* __restrict__ Wv,
                                             const float* __restrict__ Wo,
                                             const float* __restrict__ W1,
                                             const float* __restrict__ W2,
                                             const float* __restrict__ bq,
                                             const float* __restrict__ bk,
                                             const float* __restrict__ bv,
                                             const float* __restrict__ x,
                                             const float* __restrict__ alpha,
                                             const float* __restrict__ beta,
                                             unsigned short* __restrict__ wqkv,
                                             unsigned short* __restrict__ wo_b,
                                             unsigned short* __restrict__ w1_b,
                                             unsigned short* __restrict__ w2_b,
                                             float* __restrict__ bqkv,
                                             unsigned short* __restrict__ n_b) {
  const int blk = blockIdx.x;
  const float* src;
  unsigned short* dst;
  long off;
  if (blk < 1728) {            // Wq/Wk/Wv -> wqkv rows [0,2304)
    int r = blk / 576;
    src = r == 0 ? Wq : r == 1 ? Wk : Wv;
    dst = wqkv + (long)r * 589824;
    off = (long)(blk - r * 576) * 1024 + threadIdx.x * 4;
  } else if (blk < 2304) {
    src = Wo; dst = wo_b; off = (long)(blk - 1728) * 1024 + threadIdx.x * 4;
  } else if (blk < 3840) {
    src = W1; dst = w1_b; off = (long)(blk - 2304) * 1024 + threadIdx.x * 4;
  } else if (blk < 5376) {
    src = W2; dst = w2_b; off = (long)(blk - 3840) * 1024 + threadIdx.x * 4;
  } else if (blk == 5376) {    // bias concat
    for (int k = threadIdx.x; k < 2304; k += 256)
      bqkv[k] = k < 768 ? bq[k] : k < 1536 ? bk[k - 768] : bv[k - 1536];
    return;
  } else {                     // LN1: 4 rows per block
    int row = (blk - 5377) * 4 + (threadIdx.x >> 6);
    ln_row(x + (long)row * DD, alpha, beta, n_b + (long)row * DD, threadIdx.x & 63);
    return;
  }
  float4 v = *(const float4*)&src[off];
  uint2 pk;
  pk.x = cvtpk(v.x, v.y);
  pk.y = cvtpk(v.z, v.w);
  *(uint2*)&dst[off] = pk;
}

// ---------------- LN2 standalone ----------------
__global__ __launch_bounds__(256) void layernorm_k(const float* __restrict__ x,
                                                   const float* __restrict__ alpha,
                                                   const float* __restrict__ beta,
                                                   unsigned short* __restrict__ outb) {
  int row = blockIdx.x * 4 + (threadIdx.x >> 6);
  ln_row(x + (long)row * DD, alpha, beta, outb + (long)row * DD, threadIdx.x & 63);
}

// ---------------- bf16 GEMM: C[M,N] = A[M,K] * W[N,K]^T (+bias,+res,relu) ----
// 128xBN tile, BK=64, 4 waves, global_load_lds staging (m97 structure).
// XCD-chunked block swizzle (requires nwg % 8 == 0) for A-panel L2 locality.
// QSC: scale cols<768 by 0.125*log2(e) (Q pre-scale for exp2-domain attn).
template <int BN, bool RELU, bool RES, bool OUTB, bool QSC>
__global__ __launch_bounds__(256, BN == 64 ? 4 : 2)
void gemm_bt(const unsigned short* __restrict__ A,
             const unsigned short* __restrict__ W,
             const float* __restrict__ bias,
             const float* __restrict__ res,
             void* __restrict__ outp,
             int M, int N, int K) {
  __shared__ __align__(16) unsigned short As[128 * 64];
  __shared__ __align__(16) unsigned short Bs[BN * 64];
  constexpr int NF = BN / 32;   // 16-wide col frags per wave
  const int t = threadIdx.x;
  const int lane = t & 63;
  const int w = t >> 6;
  const int wr = w >> 1, wc = w & 1;
  const int l15 = lane & 15, l4 = lane >> 4;
  // XCD-chunked swizzle: contiguous chunk of blocks (sharing A-panels) per XCD
  const int nwg = gridDim.x * gridDim.y;
  const int lin = blockIdx.y * gridDim.x + blockIdx.x;
  const int u2 = (lin & 7) * (nwg >> 3) + (lin >> 3);
  const long brow = (long)(u2 / gridDim.x) * 128;
  const long bcol = (long)(u2 % gridDim.x) * BN;
  f32x4 acc[4][NF] = {};
  const int r0 = t >> 3;        // 0..31
  const int c8 = (t & 7) * 8;   // 0..56

  for (int k0 = 0; k0 < K; k0 += 64) {
    __syncthreads();
#pragma unroll
    for (int p = 0; p < 4; ++p)
      gload_lds16(&A[(brow + p * 32 + r0) * (long)K + k0 + c8],
                  (char*)As + p * 4096 + w * 1024);
#pragma unroll
    for (int p = 0; p < BN / 32; ++p)
      gload_lds16(&W[(bcol + p * 32 + r0) * (long)K + k0 + c8],
                  (char*)Bs + p * 4096 + w * 1024);
    __syncthreads();
#pragma unroll
    for (int ks = 0; ks < 2; ++ks) {
      bf16x8 a[4], b[NF];
#pragma unroll
      for (int m = 0; m < 4; ++m)
        a[m] = *(const bf16x8*)&As[(wr * 64 + m * 16 + l15) * 64 + ks * 32 + l4 * 8];
#pragma unroll
      for (int n = 0; n < NF; ++n)
        b[n] = *(const bf16x8*)&Bs[(wc * (BN / 2) + n * 16 + l15) * 64 + ks * 32 + l4 * 8];
#pragma unroll
      for (int m = 0; m < 4; ++m)
#pragma unroll
        for (int n = 0; n < NF; ++n)
          acc[m][n] = __builtin_amdgcn_mfma_f32_16x16x32_bf16(a[m], b[n], acc[m][n], 0, 0, 0);
    }
  }
#pragma unroll
  for (int n = 0; n < NF; ++n) {
    const long col = bcol + wc * (BN / 2) + n * 16 + l15;
    const float bv = bias[col];
    const float sc = (QSC && col < 768) ? 0.18033688f : 1.0f;
#pragma unroll
    for (int m = 0; m < 4; ++m) {
      const long row0 = brow + wr * 64 + m * 16 + l4 * 4;
#pragma unroll
      for (int r = 0; r < 4; ++r) {
        float v = acc[m][n][r] + bv;
        if (RELU) v = fmaxf(v, 0.0f);
        if (QSC) v *= sc;
        long o = (row0 + r) * (long)N + col;
        if (RES) v += res[o];
        if (OUTB) ((unsigned short*)outp)[o] = f2b(v);
        else ((float*)outp)[o] = v;
      }
    }
  }
}

// ---------------- flash attention v10 (v5 structure + v8 micro-opts) --------
// One block per (b,h,64-q-tile), grid 768, 256 threads, 4 waves, 32 KV tiles.
// Swapped QK^T (Q pre-scaled by 0.125*log2e at QKV epilogue). K staged
// block-cooperatively via global_load_lds (dbuf, XOR-swz). V transposed into
// key-permuted LDS (lane-local P) with v_perm. exp2 softmax, defer-max,
// max3 fmax tree, cvt_pk. Mask via per-wave ballot bitmap (scratch aliased
// onto Vt[0]); uniform branch, full path only on masked tiles.
// key->pos permutation: pos = (k5, k3, k2, k4, k1, k0)
__global__ __launch_bounds__(256, 4) void attn_kernel(const unsigned short* __restrict__ qkv,
                                                      const int* __restrict__ mask,
                                                      unsigned short* __restrict__ ctx) {
  __shared__ __align__(16) unsigned short Ks[2][64 * 64];  // K [key][d], XOR-swz
  __shared__ __align__(16) unsigned short Vt[2][64 * 64];  // V^T [d][pos], XOR-swz
  const int t = threadIdx.x, lane = t & 63, w = t >> 6;
  const int l15 = lane & 15, l4 = lane >> 4;
  // XCD-chunked swizzle (768 % 8 == 0, bijective)
  const int u = (blockIdx.x & 7) * 96 + (blockIdx.x >> 3);
  const int qt = u & 31;
  const int h = (u >> 5) % 12;
  const int b = u / 384;
  const long rowB = (long)b * SS;

  // ---- mask bitmap (scratch aliased onto Vt[0]; staged only later) ----
  unsigned bm;
  {
    int* tfl = (int*)&Vt[0][0];
    const int* mb = &mask[b * SS + t * 8];
    int4 a0 = *(const int4*)mb;
    int4 a1 = *(const int4*)(mb + 4);
    int allv = (a0.x && a0.y && a0.z && a0.w && a1.x && a1.y && a1.z && a1.w) ? 1 : 0;
    allv &= __shfl_xor(allv, 1);
    allv &= __shfl_xor(allv, 2);
    allv &= __shfl_xor(allv, 4);
    if ((t & 7) == 0) tfl[t >> 3] = allv;
    __syncthreads();
    int vv = (lane < 32) ? tfl[lane] : 1;
    bm = (unsigned)__ballot(vv);   // per-wave; bit kb = tile kb fully unmasked
    __syncthreads();               // scratch dead before Vt[0] is staged
  }

  // Q fragment (B operand): lane l15 = q, elems d = ks*32 + l4*8 + j
  bf16x8 aq[2];
#pragma unroll
  for (int ks = 0; ks < 2; ++ks)
    aq[ks] = *(const bf16x8*)&qkv[(rowB + qt * 64 + w * 16 + l15) * QKV_LD +
                                  h * 64 + ks * 32 + l4 * 8];

  // K staging (gload_lds linear dest; XOR swizzle folded into global src col)
  const int krow = w * 8 + (lane >> 3);                          // +p*32
  const int kdo = (((lane & 7) ^ (lane >> 3)) & 7) << 3;         // shorts
  const unsigned short* kgbase = &qkv[(rowB + krow) * QKV_LD + 768 + h * 64 + kdo];
  const int kread_swz = (l15 & 7) << 4;

  // V handling
  const unsigned short* vgbase = &qkv[(rowB + (t >> 3)) * QKV_LD + 1536 +
                                      h * 64 + (t & 7) * 8];
  const int vd0 = (t & 7) * 8;
  const int vpar = (t >> 3) & 1;
  const int K0 = (t >> 3) & 30;
  const unsigned psel = vpar ? 0x07060302u : 0x01000504u;  // v_perm selector

  uint4 va, vb;
  f32x4 o[4] = {};
  float mrun = -1e30f, lsum = 0.f;

#define VWRITE(buf)                                                             \
  { _Pragma("unroll") for (int p = 0; p < 2; ++p) {                             \
      uint4 vv = p ? vb : va;                                                   \
      unsigned own[4] = {vv.x, vv.y, vv.z, vv.w};                               \
      const int K0p = p * 32 + K0;                                              \
      const int pp = ((K0p & 32) | ((K0p & 12) << 1) | ((K0p & 16) >> 2) | (K0p & 2)) >> 1; \
      _Pragma("unroll") for (int j = 0; j < 4; ++j) {                           \
        unsigned part = __shfl_xor(own[j], 8);                                  \
        unsigned val = __builtin_amdgcn_perm(own[j], part, psel);               \
        int d = vd0 + 2 * j + vpar;                                             \
        int swz = (((2 * j + vpar) ^ (t & 7)) & 7) << 4;                        \
        *(unsigned*)((char*)(buf) + d * 128 + ((pp * 4) ^ swz)) = val;          \
      } } }

  // ---- prologue: stage tile 0 ----
#pragma unroll
  for (int p = 0; p < 2; ++p)
    gload_lds16(kgbase + (long)p * 32 * QKV_LD, (char*)Ks[0] + p * 4096 + w * 1024);
  va = *(const uint4*)(vgbase);
  vb = *(const uint4*)(vgbase + (long)32 * QKV_LD);
  VWRITE(Vt[0]);
  __syncthreads();

  for (int kb = 0; kb < 32; ++kb) {
    const int bi = kb & 1;
    const char* Kc = (const char*)Ks[bi];
    const char* Vc = (const char*)Vt[bi];
    // prefetch next tile (V to regs first, K direct-to-LDS after)
    if (kb < 31) {
      va = *(const uint4*)(vgbase + (long)(kb + 1) * 64 * QKV_LD);
      vb = *(const uint4*)(vgbase + ((long)(kb + 1) * 64 + 32) * QKV_LD);
#pragma unroll
      for (int p = 0; p < 2; ++p)
        gload_lds16(kgbase + ((long)(kb + 1) * 64 + p * 32) * QKV_LD,
                    (char*)Ks[bi ^ 1] + p * 4096 + w * 1024);
    }
    // ---- QK^T (swapped): S^T, col=l15=q, key=cg*16+l4*4+r; pre-scaled ----
    f32x4 s[4] = {};
    __builtin_amdgcn_s_setprio(1);
#pragma unroll
    for (int ks = 0; ks < 2; ++ks)
#pragma unroll
      for (int cg = 0; cg < 4; ++cg) {
        bf16x8 ak = *(const bf16x8*)(Kc + (cg * 16 + l15) * 128 +
                                     ((ks * 64 + l4 * 16) ^ kread_swz));
        s[cg] = __builtin_amdgcn_mfma_f32_16x16x32_bf16(ak, aq[ks], s[cg], 0, 0, 0);
      }
    __builtin_amdgcn_s_setprio(0);
    // ---- rare masked-tile path (uniform branch; never taken for all-ones) --
    if (__builtin_expect(!((bm >> kb) & 1), 0)) {
      const int* mb2 = &mask[b * SS + kb * 64 + l4 * 4];
#pragma unroll
      for (int cg = 0; cg < 4; ++cg) {
        int4 mm = *(const int4*)(mb2 + cg * 16);
        int mi[4] = {mm.x, mm.y, mm.z, mm.w};
#pragma unroll
        for (int r = 0; r < 4; ++r) s[cg][r] += mi[r] ? 0.f : -1.44269504e9f;
      }
    }
    // ---- online softmax in exp2 domain (per-q stats, q=l15) ----
    // max3-friendly reduction tree (clang fuses fmax triples to v_max3_f32)
    float t0 = fmaxf(fmaxf(s[0][0], s[0][1]), s[0][2]);
    float t1 = fmaxf(fmaxf(s[0][3], s[1][0]), s[1][1]);
    float t2 = fmaxf(fmaxf(s[1][2], s[1][3]), s[2][0]);
    float t3 = fmaxf(fmaxf(s[2][1], s[2][2]), s[2][3]);
    float t4 = fmaxf(fmaxf(s[3][0], s[3][1]), s[3][2]);
    float t5 = fmaxf(fmaxf(t0, t1), t2);
    float t6 = fmaxf(fmaxf(t3, t4), s[3][3]);
    float pmax = fmaxf(t5, t6);
    pmax = fmaxf(pmax, __shfl_xor(pmax, 16));
    pmax = fmaxf(pmax, __shfl_xor(pmax, 32));
    if (!__all(pmax <= mrun + 8.0f)) {   // defer-max (THR=8, exp2 domain)
      float mnew = fmaxf(mrun, pmax);
      float fac = __builtin_amdgcn_exp2f(mrun - mnew);
      lsum *= fac;
#pragma unroll
      for (int mg = 0; mg < 4; ++mg)
#pragma unroll
        for (int r = 0; r < 4; ++r) o[mg][r] *= fac;
      mrun = mnew;
    }
    float sum = 0.f;
#pragma unroll
    for (int cg = 0; cg < 4; ++cg)
#pragma unroll
      for (int r = 0; r < 4; ++r) {
        float p2 = __builtin_amdgcn_exp2f(s[cg][r] - mrun);
        s[cg][r] = p2;
        sum += p2;
      }
    sum += __shfl_xor(sum, 16);
    sum += __shfl_xor(sum, 32);
    lsum += sum;
    // ---- PV: O^T[d][q] += V^T . P^T ; P fragment is lane-local ----
    __builtin_amdgcn_s_setprio(1);
#pragma unroll
    for (int ks = 0; ks < 2; ++ks) {
      union { unsigned uu[4]; bf16x8 b8; } bp;
      bp.uu[0] = cvtpk(s[2 * ks][0], s[2 * ks][1]);
      bp.uu[1] = cvtpk(s[2 * ks][2], s[2 * ks][3]);
      bp.uu[2] = cvtpk(s[2 * ks + 1][0], s[2 * ks + 1][1]);
      bp.uu[3] = cvtpk(s[2 * ks + 1][2], s[2 * ks + 1][3]);
#pragma unroll
      for (int mg = 0; mg < 4; ++mg) {
        const int dv = mg * 16 + l15;
        const int sv = ((dv ^ (dv >> 3)) & 7) << 4;
        bf16x8 av = *(const bf16x8*)(Vc + dv * 128 + ((ks * 64 + l4 * 16) ^ sv));
        o[mg] = __builtin_amdgcn_mfma_f32_16x16x32_bf16(av, bp.b8, o[mg], 0, 0, 0);
      }
    }
    __builtin_amdgcn_s_setprio(0);
    // ---- write next V tile (vreg landed under compute) ----
    if (kb < 31) VWRITE(Vt[bi ^ 1]);
    __syncthreads();
  }
  // ---- epilogue: O^T regs hold col q=l15, row d=mg*16+l4*4+r ----
  const float inv = 1.0f / lsum;
  const long obase = (rowB + qt * 64 + w * 16 + l15) * DD + h * 64 + l4 * 4;
#pragma unroll
  for (int mg = 0; mg < 4; ++mg) {
    *(unsigned*)&ctx[obase + mg * 16] = cvtpk(o[mg][0] * inv, o[mg][1] * inv);
    *(unsigned*)&ctx[obase + mg * 16 + 2] = cvtpk(o[mg][2] * inv, o[mg][3] * inv);
  }
#undef VWRITE
}

// ---------------- workspace layout (bytes) ----------------
static const size_t OFF_WQKV = 0;          // 2304*768*2  = 3538944
static const size_t OFF_WO = 3538944;      // 768*768*2   = 1179648
static const size_t OFF_W1 = 4718592;      // 2048*768*2  = 3145728
static const size_t OFF_W2 = 7864320;      // 768*2048*2  = 3145728
static const size_t OFF_BQKV = 11010048;   // 2304*4
static const size_t OFF_N = 11019264;      // 4096*768*2  (reused for n2)
static const size_t OFF_QKV = 17310720;    // 4096*2304*2 (reused for h)
static const size_t OFF_CTX = 36185088;    // 4096*768*2
static const size_t OFF_X1 = 42476544;     // 4096*768*4
// total = 55059456 bytes

extern "C" void kernel_launch(void* const* d_in, const int* in_sizes, int n_in,
                              void* d_out, int out_size, void* d_ws, size_t ws_size,
                              hipStream_t stream) {
  (void)in_sizes; (void)n_in; (void)out_size; (void)ws_size;
  const float* x = (const float*)d_in[0];
  const int* mask = (const int*)d_in[1];
  const float* Wq = (const float*)d_in[2];
  const float* bq = (const float*)d_in[3];
  const float* Wk = (const float*)d_in[4];
  const float* bk = (const float*)d_in[5];
  const float* Wv = (const float*)d_in[6];
  const float* bv = (const float*)d_in[7];
  const float* Wo = (const float*)d_in[8];
  const float* bo = (const float*)d_in[9];
  const float* W1 = (const float*)d_in[10];
  const float* b1 = (const float*)d_in[11];
  const float* W2 = (const float*)d_in[12];
  const float* b2 = (const float*)d_in[13];
  const float* alpha = (const float*)d_in[14];
  const float* beta = (const float*)d_in[15];

  char* ws = (char*)d_ws;
  unsigned short* wqkv = (unsigned short*)(ws + OFF_WQKV);
  unsigned short* wo_b = (unsigned short*)(ws + OFF_WO);
  unsigned short* w1_b = (unsigned short*)(ws + OFF_W1);
  unsigned short* w2_b = (unsigned short*)(ws + OFF_W2);
  float* bqkv = (float*)(ws + OFF_BQKV);
  unsigned short* n_b = (unsigned short*)(ws + OFF_N);
  unsigned short* qkv_b = (unsigned short*)(ws + OFF_QKV);
  unsigned short* h_b = qkv_b;  // reuse after attention
  unsigned short* ctx_b = (unsigned short*)(ws + OFF_CTX);
  float* x1_f = (float*)(ws + OFF_X1);
  float* out_f = (float*)d_out;

  // weights->bf16 + bias concat + LN1 in one launch (5377 cvt/bias + 1024 LN)
  pre_k<<<6401, 256, 0, stream>>>(Wq, Wk, Wv, Wo, W1, W2, bq, bk, bv,
                                  x, alpha, beta, wqkv, wo_b, w1_b, w2_b, bqkv, n_b);
  // fused QKV GEMM: [4096,768] x [2304,768]^T -> [4096,2304] bf16, Q pre-scaled
  gemm_bt<128, false, false, true, true><<<dim3(18, 32), 256, 0, stream>>>(
      n_b, wqkv, bqkv, nullptr, qkv_b, BSR, QKV_LD, DD);
  // attention: one block per (b,h,qt), full KV
  attn_kernel<<<768, 256, 0, stream>>>(qkv_b, mask, ctx_b);
  // Wo GEMM + residual(x) -> x1 fp32 (BN=64: 384 blocks)
  gemm_bt<64, false, true, false, false><<<dim3(12, 32), 256, 0, stream>>>(
      ctx_b, wo_b, bo, x, x1_f, BSR, DD, DD);
  // LN2
  layernorm_k<<<1024, 256, 0, stream>>>(x1_f, alpha, beta, n_b);
  // FFN1 + relu -> h bf16
  gemm_bt<128, true, false, true, false><<<dim3(16, 32), 256, 0, stream>>>(
      n_b, w1_b, b1, nullptr, h_b, BSR, DFFF, DD);
  // FFN2 + residual(x1) -> out fp32 (BN=64: 384 blocks)
  gemm_bt<64, false, true, false, false><<<dim3(12, 32), 256, 0, stream>>>(
      h_b, w2_b, b2, x1_f, out_f, BSR, DD, DFFF);
}